// Round 1
// baseline (2391.634 us; speedup 1.0000x reference)
//
#include <hip/hip_runtime.h>
#include <hip/hip_bf16.h>

#define N_NODES  100000
#define N_EDGES  600000
#define D        128
#define N_GRAPHS 512

// ---------------------------------------------------------------------------
// deg[i] = 1 (self-loop), then +1 per in-edge; then in-place rsqrt -> dis[i]
// ---------------------------------------------------------------------------
__global__ void k_init_deg(float* __restrict__ deg) {
    int i = blockIdx.x * blockDim.x + threadIdx.x;
    if (i < N_NODES) deg[i] = 1.0f;
}

__global__ void k_deg_scatter(const int* __restrict__ dst, float* __restrict__ deg) {
    int e = blockIdx.x * blockDim.x + threadIdx.x;
    if (e < N_EDGES) atomicAdd(&deg[dst[e]], 1.0f);
}

__global__ void k_rsqrt(float* __restrict__ deg) {
    int i = blockIdx.x * blockDim.x + threadIdx.x;
    if (i < N_NODES) deg[i] = rsqrtf(deg[i]);   // deg >= 1 always
}

// ---------------------------------------------------------------------------
// Y[n, 0:128] = (RELU_IN ? relu(X) : X)[n, 0:128] @ W[128,128]
// 64-row tile, 512 threads, W (64KB) + padded X tile (33.8KB) in LDS.
// Each thread: 4 rows x 4 cols register block.
// ---------------------------------------------------------------------------
template<int RELU_IN>
__global__ __launch_bounds__(512) void k_gemm(const float* __restrict__ X,
                                              const float* __restrict__ W,
                                              float* __restrict__ Y) {
    __shared__ float ws[128][128];   // 64 KB
    __shared__ float xs[64][132];    // padded leading dim -> no bank conflicts

    const int tid  = threadIdx.x;
    const int row0 = blockIdx.x * 64;

    // stage W: 16384 floats = 4096 float4 / 512 threads = 8 each
    const float4* W4  = (const float4*)W;
    float4*       ws4 = (float4*)&ws[0][0];
    #pragma unroll
    for (int i = tid; i < 4096; i += 512) ws4[i] = W4[i];

    // stage X tile: 64 rows x 32 float4
    #pragma unroll
    for (int i = tid; i < 2048; i += 512) {
        int r  = i >> 5;
        int c4 = i & 31;
        float4 v = make_float4(0.f, 0.f, 0.f, 0.f);
        if (row0 + r < N_NODES)
            v = ((const float4*)(X + (size_t)(row0 + r) * D))[c4];
        if (RELU_IN) {
            v.x = fmaxf(v.x, 0.f); v.y = fmaxf(v.y, 0.f);
            v.z = fmaxf(v.z, 0.f); v.w = fmaxf(v.w, 0.f);
        }
        xs[r][c4 * 4 + 0] = v.x; xs[r][c4 * 4 + 1] = v.y;
        xs[r][c4 * 4 + 2] = v.z; xs[r][c4 * 4 + 3] = v.w;
    }
    __syncthreads();

    const int rg = tid >> 5;   // 0..15 -> rows rg*4 .. rg*4+3
    const int cg = tid & 31;   // 0..31 -> cols cg*4 .. cg*4+3

    float acc[4][4];
    #pragma unroll
    for (int i = 0; i < 4; ++i)
        #pragma unroll
        for (int j = 0; j < 4; ++j) acc[i][j] = 0.f;

    #pragma unroll 4
    for (int k = 0; k < 128; ++k) {
        float4 wv = *(const float4*)&ws[k][cg * 4];
        float x0 = xs[rg * 4 + 0][k];
        float x1 = xs[rg * 4 + 1][k];
        float x2 = xs[rg * 4 + 2][k];
        float x3 = xs[rg * 4 + 3][k];
        acc[0][0] += x0 * wv.x; acc[0][1] += x0 * wv.y; acc[0][2] += x0 * wv.z; acc[0][3] += x0 * wv.w;
        acc[1][0] += x1 * wv.x; acc[1][1] += x1 * wv.y; acc[1][2] += x1 * wv.z; acc[1][3] += x1 * wv.w;
        acc[2][0] += x2 * wv.x; acc[2][1] += x2 * wv.y; acc[2][2] += x2 * wv.z; acc[2][3] += x2 * wv.w;
        acc[3][0] += x3 * wv.x; acc[3][1] += x3 * wv.y; acc[3][2] += x3 * wv.z; acc[3][3] += x3 * wv.w;
    }

    #pragma unroll
    for (int i = 0; i < 4; ++i) {
        int r = row0 + rg * 4 + i;
        if (r < N_NODES) {
            float4 o = make_float4(acc[i][0], acc[i][1], acc[i][2], acc[i][3]);
            ((float4*)(Y + (size_t)r * D))[cg] = o;
        }
    }
}

// ---------------------------------------------------------------------------
// AGG[i,:] = bias[:] + dis[i]^2 * H[i,:]      (self-loop term + bias init)
// ---------------------------------------------------------------------------
__global__ void k_agg_init(const float* __restrict__ H, const float* __restrict__ dis,
                           const float* __restrict__ bias, float* __restrict__ AGG) {
    int idx = blockIdx.x * blockDim.x + threadIdx.x;   // float4 index, N_NODES*32 total
    if (idx >= N_NODES * 32) return;
    int node = idx >> 5;
    int l    = idx & 31;
    float dsq = dis[node];
    dsq *= dsq;
    float4 h = ((const float4*)H)[idx];
    float4 b = ((const float4*)bias)[l];
    float4 o = make_float4(b.x + dsq * h.x, b.y + dsq * h.y,
                           b.z + dsq * h.z, b.w + dsq * h.w);
    ((float4*)AGG)[idx] = o;
}

// ---------------------------------------------------------------------------
// For each edge e: AGG[dst[e], :] += dis[src]*dis[dst] * H[src[e], :]
// 32 threads per edge, float4 gather + 4 scalar atomics per thread.
// ---------------------------------------------------------------------------
__global__ __launch_bounds__(256) void k_edge_scatter(const int* __restrict__ src,
                                                      const int* __restrict__ dst,
                                                      const float* __restrict__ dis,
                                                      const float* __restrict__ H,
                                                      float* __restrict__ AGG) {
    int t = blockIdx.x * 256 + threadIdx.x;
    int e = t >> 5;
    if (e >= N_EDGES) return;
    int l = t & 31;
    int s = src[e];
    int d = dst[e];
    float nrm = dis[s] * dis[d];
    float4 v = ((const float4*)(H + (size_t)s * D))[l];
    float* o = AGG + (size_t)d * D + (size_t)l * 4;
    atomicAdd(o + 0, nrm * v.x);
    atomicAdd(o + 1, nrm * v.y);
    atomicAdd(o + 2, nrm * v.z);
    atomicAdd(o + 3, nrm * v.w);
}

// ---------------------------------------------------------------------------
// One block per graph: binary-search node range in sorted batch, mean of
// relu(H) over rows, then fused tiny head: out[g,c] = pooled . Wl[:,c] + bl[c]
// ---------------------------------------------------------------------------
__global__ __launch_bounds__(128) void k_pool_head(const float* __restrict__ H,
                                                   const int* __restrict__ batch,
                                                   const float* __restrict__ Wl,
                                                   const float* __restrict__ bl,
                                                   float* __restrict__ out) {
    int g = blockIdx.x;
    int f = threadIdx.x;

    // lower_bound(batch, g) / lower_bound(batch, g+1)
    int lo = 0, hi = N_NODES;
    while (lo < hi) { int mid = (lo + hi) >> 1; if (batch[mid] < g) lo = mid + 1; else hi = mid; }
    int s = lo;
    lo = s; hi = N_NODES;
    while (lo < hi) { int mid = (lo + hi) >> 1; if (batch[mid] < g + 1) lo = mid + 1; else hi = mid; }
    int e = lo;

    float sum = 0.f;
    for (int i = s; i < e; ++i)
        sum += fmaxf(H[(size_t)i * D + f], 0.f);

    float cnt = (float)((e - s) > 0 ? (e - s) : 1);
    float p   = sum / cnt;

    __shared__ float s0[128];
    __shared__ float s1[128];
    s0[f] = p * Wl[f * 2 + 0];
    s1[f] = p * Wl[f * 2 + 1];
    __syncthreads();
    #pragma unroll
    for (int off = 64; off > 0; off >>= 1) {
        if (f < off) { s0[f] += s0[f + off]; s1[f] += s1[f + off]; }
        __syncthreads();
    }
    if (f == 0) {
        out[g * 2 + 0] = s0[0] + bl[0];
        out[g * 2 + 1] = s1[0] + bl[1];
    }
}

// ---------------------------------------------------------------------------
extern "C" void kernel_launch(void* const* d_in, const int* in_sizes, int n_in,
                              void* d_out, int out_size, void* d_ws, size_t ws_size,
                              hipStream_t stream) {
    const float* x     = (const float*)d_in[0];
    const int*   ei    = (const int*)  d_in[1];   // [2, E] int
    const int*   batch = (const int*)  d_in[2];
    const float* W1    = (const float*)d_in[3];
    const float* b1    = (const float*)d_in[4];
    const float* W2    = (const float*)d_in[5];
    const float* b2    = (const float*)d_in[6];
    const float* Wl    = (const float*)d_in[7];
    const float* bl    = (const float*)d_in[8];
    float* out = (float*)d_out;

    char* ws = (char*)d_ws;
    float* bufA = (float*)(ws);                       // 51.2 MB: h = X@W
    float* bufB = (float*)(ws + 51200000);            // 51.2 MB: aggregation
    float* dis  = (float*)(ws + 102400000);           // 400 KB: deg -> rsqrt

    const int* srcIdx = ei;             // edge_index[0] : message source
    const int* dstIdx = ei + N_EDGES;   // edge_index[1] : aggregation target

    k_init_deg   <<<(N_NODES + 255) / 256, 256, 0, stream>>>(dis);
    k_deg_scatter<<<(N_EDGES + 255) / 256, 256, 0, stream>>>(dstIdx, dis);
    k_rsqrt      <<<(N_NODES + 255) / 256, 256, 0, stream>>>(dis);

    // layer 1
    k_gemm<0>       <<<(N_NODES + 63) / 64, 512, 0, stream>>>(x, W1, bufA);
    k_agg_init      <<<(N_NODES * 32 + 255) / 256, 256, 0, stream>>>(bufA, dis, b1, bufB);
    k_edge_scatter  <<<(N_EDGES * 32 + 255) / 256, 256, 0, stream>>>(srcIdx, dstIdx, dis, bufA, bufB);

    // layer 2 (relu fused into GEMM input load)
    k_gemm<1>       <<<(N_NODES + 63) / 64, 512, 0, stream>>>(bufB, W2, bufA);
    k_agg_init      <<<(N_NODES * 32 + 255) / 256, 256, 0, stream>>>(bufA, dis, b2, bufB);
    k_edge_scatter  <<<(N_EDGES * 32 + 255) / 256, 256, 0, stream>>>(srcIdx, dstIdx, dis, bufA, bufB);

    // relu + mean-pool + linear head (fused)
    k_pool_head     <<<N_GRAPHS, 128, 0, stream>>>(bufB, batch, Wl, bl, out);
}

// Round 2
// 519.807 us; speedup vs baseline: 4.6010x; 4.6010x over previous
//
#include <hip/hip_runtime.h>
#include <hip/hip_bf16.h>

#define N_NODES  100000
#define N_EDGES  600000
#define D        128
#define N_GRAPHS 512

#define CH   512                       // scan chunk size
#define NB   ((N_NODES + CH - 1) / CH) // 196 chunks

// ---------------------------------------------------------------------------
// zero int arrays (cnt and pos)
// ---------------------------------------------------------------------------
__global__ void k_zero2(int* __restrict__ a, int* __restrict__ b) {
    int i = blockIdx.x * blockDim.x + threadIdx.x;
    if (i < N_NODES) { a[i] = 0; b[i] = 0; }
}

// cnt[d] = number of in-edges of d
__global__ void k_hist(const int* __restrict__ dst, int* __restrict__ cnt) {
    int e = blockIdx.x * blockDim.x + threadIdx.x;
    if (e < N_EDGES) atomicAdd(&cnt[dst[e]], 1);
}

// dis[i] = rsqrt(cnt[i] + 1)   (self-loop included; deg >= 1)
__global__ void k_dis(const int* __restrict__ cnt, float* __restrict__ dis) {
    int i = blockIdx.x * blockDim.x + threadIdx.x;
    if (i < N_NODES) dis[i] = rsqrtf((float)(cnt[i] + 1));
}

// ---------------------------------------------------------------------------
// 3-pass exclusive scan of cnt -> off  (Hillis-Steele in LDS, 512/block)
// ---------------------------------------------------------------------------
__global__ __launch_bounds__(CH) void k_scanA(const int* __restrict__ cnt,
                                              int* __restrict__ off,
                                              int* __restrict__ chunk_sums) {
    __shared__ int s[CH];
    int tid = threadIdx.x;
    int gid = blockIdx.x * CH + tid;
    int v = (gid < N_NODES) ? cnt[gid] : 0;
    s[tid] = v;
    __syncthreads();
    #pragma unroll
    for (int o = 1; o < CH; o <<= 1) {
        int t = (tid >= o) ? s[tid - o] : 0;
        __syncthreads();
        s[tid] += t;
        __syncthreads();
    }
    if (gid < N_NODES) off[gid] = s[tid] - v;      // exclusive within chunk
    if (tid == CH - 1) chunk_sums[blockIdx.x] = s[tid];
}

__global__ __launch_bounds__(CH) void k_scanB(const int* __restrict__ chunk_sums,
                                              int* __restrict__ chunk_offs,
                                              int* __restrict__ off) {
    __shared__ int s[CH];
    int tid = threadIdx.x;
    int v = (tid < NB) ? chunk_sums[tid] : 0;
    s[tid] = v;
    __syncthreads();
    #pragma unroll
    for (int o = 1; o < CH; o <<= 1) {
        int t = (tid >= o) ? s[tid - o] : 0;
        __syncthreads();
        s[tid] += t;
        __syncthreads();
    }
    if (tid < NB) chunk_offs[tid] = s[tid] - v;    // exclusive chunk offsets
    if (tid == NB - 1) off[N_NODES] = s[tid];      // grand total = N_EDGES
}

__global__ __launch_bounds__(CH) void k_scanC(int* __restrict__ off,
                                              const int* __restrict__ chunk_offs) {
    int gid = blockIdx.x * CH + threadIdx.x;
    if (gid < N_NODES) off[gid] += chunk_offs[blockIdx.x];
}

// fill CSR: csr_src[j], csr_nrm[j] for j in [off[d], off[d+1])
__global__ void k_fill(const int* __restrict__ src, const int* __restrict__ dst,
                       const float* __restrict__ dis,
                       const int* __restrict__ off, int* __restrict__ pos,
                       int* __restrict__ csr_src, float* __restrict__ csr_nrm) {
    int e = blockIdx.x * blockDim.x + threadIdx.x;
    if (e >= N_EDGES) return;
    int s = src[e];
    int d = dst[e];
    int j = off[d] + atomicAdd(&pos[d], 1);
    csr_src[j] = s;
    csr_nrm[j] = dis[s] * dis[d];
}

// ---------------------------------------------------------------------------
// Y[n, 0:128] = (RELU_IN ? relu(X) : X)[n, 0:128] @ W[128,128]
// ---------------------------------------------------------------------------
template<int RELU_IN>
__global__ __launch_bounds__(512) void k_gemm(const float* __restrict__ X,
                                              const float* __restrict__ W,
                                              float* __restrict__ Y) {
    __shared__ float ws[128][128];
    __shared__ float xs[64][132];

    const int tid  = threadIdx.x;
    const int row0 = blockIdx.x * 64;

    const float4* W4  = (const float4*)W;
    float4*       ws4 = (float4*)&ws[0][0];
    #pragma unroll
    for (int i = tid; i < 4096; i += 512) ws4[i] = W4[i];

    #pragma unroll
    for (int i = tid; i < 2048; i += 512) {
        int r  = i >> 5;
        int c4 = i & 31;
        float4 v = make_float4(0.f, 0.f, 0.f, 0.f);
        if (row0 + r < N_NODES)
            v = ((const float4*)(X + (size_t)(row0 + r) * D))[c4];
        if (RELU_IN) {
            v.x = fmaxf(v.x, 0.f); v.y = fmaxf(v.y, 0.f);
            v.z = fmaxf(v.z, 0.f); v.w = fmaxf(v.w, 0.f);
        }
        xs[r][c4 * 4 + 0] = v.x; xs[r][c4 * 4 + 1] = v.y;
        xs[r][c4 * 4 + 2] = v.z; xs[r][c4 * 4 + 3] = v.w;
    }
    __syncthreads();

    const int rg = tid >> 5;
    const int cg = tid & 31;

    float acc[4][4];
    #pragma unroll
    for (int i = 0; i < 4; ++i)
        #pragma unroll
        for (int j = 0; j < 4; ++j) acc[i][j] = 0.f;

    #pragma unroll 4
    for (int k = 0; k < 128; ++k) {
        float4 wv = *(const float4*)&ws[k][cg * 4];
        float x0 = xs[rg * 4 + 0][k];
        float x1 = xs[rg * 4 + 1][k];
        float x2 = xs[rg * 4 + 2][k];
        float x3 = xs[rg * 4 + 3][k];
        acc[0][0] += x0 * wv.x; acc[0][1] += x0 * wv.y; acc[0][2] += x0 * wv.z; acc[0][3] += x0 * wv.w;
        acc[1][0] += x1 * wv.x; acc[1][1] += x1 * wv.y; acc[1][2] += x1 * wv.z; acc[1][3] += x1 * wv.w;
        acc[2][0] += x2 * wv.x; acc[2][1] += x2 * wv.y; acc[2][2] += x2 * wv.z; acc[2][3] += x2 * wv.w;
        acc[3][0] += x3 * wv.x; acc[3][1] += x3 * wv.y; acc[3][2] += x3 * wv.z; acc[3][3] += x3 * wv.w;
    }

    #pragma unroll
    for (int i = 0; i < 4; ++i) {
        int r = row0 + rg * 4 + i;
        if (r < N_NODES) {
            float4 o = make_float4(acc[i][0], acc[i][1], acc[i][2], acc[i][3]);
            ((float4*)(Y + (size_t)r * D))[cg] = o;
        }
    }
}

// ---------------------------------------------------------------------------
// Gather-aggregate: one wave (64 lanes) per node, float2 per lane.
// AGG[n,:] = bias + dis[n]^2 * H[n,:] + sum_j nrm[j] * H[csr_src[j],:]
// ---------------------------------------------------------------------------
__global__ __launch_bounds__(256) void k_agg(const float* __restrict__ H,
                                             const float* __restrict__ dis,
                                             const float* __restrict__ bias,
                                             const int* __restrict__ off,
                                             const int* __restrict__ csr_src,
                                             const float* __restrict__ csr_nrm,
                                             float* __restrict__ AGG) {
    int wid = (blockIdx.x * 256 + threadIdx.x) >> 6;   // node id (uniform per wave)
    if (wid >= N_NODES) return;
    int lane = threadIdx.x & 63;

    const float2* H2 = (const float2*)H;
    float2 b = ((const float2*)bias)[lane];
    float  dn = dis[wid];
    float2 h  = H2[(size_t)wid * 64 + lane];
    float2 acc = make_float2(b.x + dn * dn * h.x, b.y + dn * dn * h.y);

    int jb = off[wid];
    int je = off[wid + 1];
    for (int j = jb; j < je; ++j) {
        int   s   = csr_src[j];
        float nrm = csr_nrm[j];
        float2 v  = H2[(size_t)s * 64 + lane];
        acc.x += nrm * v.x;
        acc.y += nrm * v.y;
    }
    ((float2*)AGG)[(size_t)wid * 64 + lane] = acc;
}

// ---------------------------------------------------------------------------
// One block per graph: relu + mean-pool + tiny linear head
// ---------------------------------------------------------------------------
__global__ __launch_bounds__(128) void k_pool_head(const float* __restrict__ H,
                                                   const int* __restrict__ batch,
                                                   const float* __restrict__ Wl,
                                                   const float* __restrict__ bl,
                                                   float* __restrict__ out) {
    int g = blockIdx.x;
    int f = threadIdx.x;

    int lo = 0, hi = N_NODES;
    while (lo < hi) { int mid = (lo + hi) >> 1; if (batch[mid] < g) lo = mid + 1; else hi = mid; }
    int s = lo;
    lo = s; hi = N_NODES;
    while (lo < hi) { int mid = (lo + hi) >> 1; if (batch[mid] < g + 1) lo = mid + 1; else hi = mid; }
    int e = lo;

    float sum = 0.f;
    for (int i = s; i < e; ++i)
        sum += fmaxf(H[(size_t)i * D + f], 0.f);

    float cnt = (float)((e - s) > 0 ? (e - s) : 1);
    float p   = sum / cnt;

    __shared__ float s0[128];
    __shared__ float s1[128];
    s0[f] = p * Wl[f * 2 + 0];
    s1[f] = p * Wl[f * 2 + 1];
    __syncthreads();
    #pragma unroll
    for (int off2 = 64; off2 > 0; off2 >>= 1) {
        if (f < off2) { s0[f] += s0[f + off2]; s1[f] += s1[f + off2]; }
        __syncthreads();
    }
    if (f == 0) {
        out[g * 2 + 0] = s0[0] + bl[0];
        out[g * 2 + 1] = s1[0] + bl[1];
    }
}

// ---------------------------------------------------------------------------
extern "C" void kernel_launch(void* const* d_in, const int* in_sizes, int n_in,
                              void* d_out, int out_size, void* d_ws, size_t ws_size,
                              hipStream_t stream) {
    const float* x     = (const float*)d_in[0];
    const int*   ei    = (const int*)  d_in[1];
    const int*   batch = (const int*)  d_in[2];
    const float* W1    = (const float*)d_in[3];
    const float* b1    = (const float*)d_in[4];
    const float* W2    = (const float*)d_in[5];
    const float* b2    = (const float*)d_in[6];
    const float* Wl    = (const float*)d_in[7];
    const float* bl    = (const float*)d_in[8];
    float* out = (float*)d_out;

    char* ws = (char*)d_ws;
    float* bufA       = (float*)(ws);                  // 51.2 MB
    float* bufB       = (float*)(ws + 51200000);       // 51.2 MB
    float* dis        = (float*)(ws + 102400000);      // 400 KB
    int*   cnt        = (int*)  (ws + 102800000);      // 400 KB
    int*   off        = (int*)  (ws + 103200000);      // 400 KB + 16 (N+1 ints)
    int*   pos        = (int*)  (ws + 103600016);      // 400 KB
    int*   chunk_sums = (int*)  (ws + 104000016);      // 800 B
    int*   chunk_offs = (int*)  (ws + 104000816);      // 800 B
    int*   csr_src    = (int*)  (ws + 104001616);      // 2.4 MB
    float* csr_nrm    = (float*)(ws + 106401616);      // 2.4 MB
    // total: 108,801,616 bytes

    const int* srcIdx = ei;
    const int* dstIdx = ei + N_EDGES;

    // ---- CSR build ----
    k_zero2<<<(N_NODES + 255) / 256, 256, 0, stream>>>(cnt, pos);
    k_hist <<<(N_EDGES + 255) / 256, 256, 0, stream>>>(dstIdx, cnt);
    k_dis  <<<(N_NODES + 255) / 256, 256, 0, stream>>>(cnt, dis);
    k_scanA<<<NB, CH, 0, stream>>>(cnt, off, chunk_sums);
    k_scanB<<<1,  CH, 0, stream>>>(chunk_sums, chunk_offs, off);
    k_scanC<<<NB, CH, 0, stream>>>(off, chunk_offs);
    k_fill <<<(N_EDGES + 255) / 256, 256, 0, stream>>>(srcIdx, dstIdx, dis, off, pos,
                                                       csr_src, csr_nrm);

    // ---- layer 1 ----
    k_gemm<0><<<(N_NODES + 63) / 64, 512, 0, stream>>>(x, W1, bufA);
    k_agg    <<<(N_NODES * 64 + 255) / 256, 256, 0, stream>>>(bufA, dis, b1, off,
                                                              csr_src, csr_nrm, bufB);
    // ---- layer 2 (relu fused into GEMM input) ----
    k_gemm<1><<<(N_NODES + 63) / 64, 512, 0, stream>>>(bufB, W2, bufA);
    k_agg    <<<(N_NODES * 64 + 255) / 256, 256, 0, stream>>>(bufA, dis, b2, off,
                                                              csr_src, csr_nrm, bufB);
    // ---- relu + mean-pool + head ----
    k_pool_head<<<N_GRAPHS, 128, 0, stream>>>(bufB, batch, Wl, bl, out);
}

// Round 3
// 414.995 us; speedup vs baseline: 5.7630x; 1.2526x over previous
//
#include <hip/hip_runtime.h>
#include <hip/hip_bf16.h>

#define N_NODES  100000
#define N_EDGES  600000
#define D        128
#define N_GRAPHS 512

#define CH   512                       // scan chunk size
#define NB   ((N_NODES + CH - 1) / CH) // 196 chunks

// ---------------------------------------------------------------------------
__global__ void k_zero2(int* __restrict__ a, int* __restrict__ b) {
    int i = blockIdx.x * blockDim.x + threadIdx.x;
    if (i < N_NODES) { a[i] = 0; b[i] = 0; }
}

__global__ void k_hist(const int* __restrict__ dst, int* __restrict__ cnt) {
    int e = blockIdx.x * blockDim.x + threadIdx.x;
    if (e < N_EDGES) atomicAdd(&cnt[dst[e]], 1);
}

// ---------------------------------------------------------------------------
// 3-pass exclusive scan of cnt -> off; scanA also emits dis = rsqrt(cnt+1)
// ---------------------------------------------------------------------------
__global__ __launch_bounds__(CH) void k_scanA(const int* __restrict__ cnt,
                                              int* __restrict__ off,
                                              int* __restrict__ chunk_sums,
                                              float* __restrict__ dis) {
    __shared__ int s[CH];
    int tid = threadIdx.x;
    int gid = blockIdx.x * CH + tid;
    int v = (gid < N_NODES) ? cnt[gid] : 0;
    if (gid < N_NODES) dis[gid] = rsqrtf((float)(v + 1));
    s[tid] = v;
    __syncthreads();
    #pragma unroll
    for (int o = 1; o < CH; o <<= 1) {
        int t = (tid >= o) ? s[tid - o] : 0;
        __syncthreads();
        s[tid] += t;
        __syncthreads();
    }
    if (gid < N_NODES) off[gid] = s[tid] - v;
    if (tid == CH - 1) chunk_sums[blockIdx.x] = s[tid];
}

__global__ __launch_bounds__(CH) void k_scanB(const int* __restrict__ chunk_sums,
                                              int* __restrict__ chunk_offs,
                                              int* __restrict__ off) {
    __shared__ int s[CH];
    int tid = threadIdx.x;
    int v = (tid < NB) ? chunk_sums[tid] : 0;
    s[tid] = v;
    __syncthreads();
    #pragma unroll
    for (int o = 1; o < CH; o <<= 1) {
        int t = (tid >= o) ? s[tid - o] : 0;
        __syncthreads();
        s[tid] += t;
        __syncthreads();
    }
    if (tid < NB) chunk_offs[tid] = s[tid] - v;
    if (tid == NB - 1) off[N_NODES] = s[tid];
}

__global__ __launch_bounds__(CH) void k_scanC(int* __restrict__ off,
                                              const int* __restrict__ chunk_offs) {
    int gid = blockIdx.x * CH + threadIdx.x;
    if (gid < N_NODES) off[gid] += chunk_offs[blockIdx.x];
}

__global__ void k_fill(const int* __restrict__ src, const int* __restrict__ dst,
                       const float* __restrict__ dis,
                       const int* __restrict__ off, int* __restrict__ pos,
                       int* __restrict__ csr_src, float* __restrict__ csr_nrm) {
    int e = blockIdx.x * blockDim.x + threadIdx.x;
    if (e >= N_EDGES) return;
    int s = src[e];
    int d = dst[e];
    int j = off[d] + atomicAdd(&pos[d], 1);
    csr_src[j] = s;
    csr_nrm[j] = dis[s] * dis[d];
}

// ---------------------------------------------------------------------------
// Y = (RELU_IN ? relu(X) : X) @ W.   64-row tile, 512 threads.
// LDS: W K-chunk [64][128] (32 KB) + transposed X tile xst[128][65] (33.3 KB)
// => 66 KB => 2 blocks/CU (16 waves).  Inner loop: 2 x ds_read_b128 per k.
// ---------------------------------------------------------------------------
template<int RELU_IN>
__global__ __launch_bounds__(512, 4) void k_gemm(const float* __restrict__ X,
                                                 const float* __restrict__ W,
                                                 float* __restrict__ Y) {
    __shared__ float ws[64][128];    // 32 KB  (one K-chunk of W)
    __shared__ float xst[128][65];   // 33.3 KB (X tile, transposed, padded)

    const int tid  = threadIdx.x;
    const int row0 = blockIdx.x * 64;

    // stage X tile transposed: thread i loads row r=i>>5, float4 c4=i&31
    #pragma unroll
    for (int i = tid; i < 2048; i += 512) {
        int r  = i >> 5;
        int c4 = i & 31;
        float4 v = make_float4(0.f, 0.f, 0.f, 0.f);
        if (row0 + r < N_NODES)
            v = ((const float4*)(X + (size_t)(row0 + r) * D))[c4];
        if (RELU_IN) {
            v.x = fmaxf(v.x, 0.f); v.y = fmaxf(v.y, 0.f);
            v.z = fmaxf(v.z, 0.f); v.w = fmaxf(v.w, 0.f);
        }
        xst[c4 * 4 + 0][r] = v.x;
        xst[c4 * 4 + 1][r] = v.y;
        xst[c4 * 4 + 2][r] = v.z;
        xst[c4 * 4 + 3][r] = v.w;
    }

    const int rg = tid >> 5;   // 0..15 -> rows rg*4..+3
    const int cg = tid & 31;   // 0..31 -> cols cg*4..+3

    float acc[4][4];
    #pragma unroll
    for (int i = 0; i < 4; ++i)
        #pragma unroll
        for (int j = 0; j < 4; ++j) acc[i][j] = 0.f;

    #pragma unroll
    for (int chunk = 0; chunk < 2; ++chunk) {
        __syncthreads();   // xst ready (chunk 0) / previous ws consumed (chunk 1)
        // stage W chunk: 8192 floats = 2048 float4, 4 per thread
        const float4* Wc = (const float4*)(W + chunk * 64 * D);
        float4* ws4 = (float4*)&ws[0][0];
        #pragma unroll
        for (int i = tid; i < 2048; i += 512) ws4[i] = Wc[i];
        __syncthreads();

        #pragma unroll 8
        for (int kk = 0; kk < 64; ++kk) {
            float4 xv = *(const float4*)&xst[chunk * 64 + kk][rg * 4];
            float4 wv = *(const float4*)&ws[kk][cg * 4];
            acc[0][0] += xv.x * wv.x; acc[0][1] += xv.x * wv.y; acc[0][2] += xv.x * wv.z; acc[0][3] += xv.x * wv.w;
            acc[1][0] += xv.y * wv.x; acc[1][1] += xv.y * wv.y; acc[1][2] += xv.y * wv.z; acc[1][3] += xv.y * wv.w;
            acc[2][0] += xv.z * wv.x; acc[2][1] += xv.z * wv.y; acc[2][2] += xv.z * wv.z; acc[2][3] += xv.z * wv.w;
            acc[3][0] += xv.w * wv.x; acc[3][1] += xv.w * wv.y; acc[3][2] += xv.w * wv.z; acc[3][3] += xv.w * wv.w;
        }
    }

    #pragma unroll
    for (int i = 0; i < 4; ++i) {
        int r = row0 + rg * 4 + i;
        if (r < N_NODES) {
            float4 o = make_float4(acc[i][0], acc[i][1], acc[i][2], acc[i][3]);
            ((float4*)(Y + (size_t)r * D))[cg] = o;
        }
    }
}

// ---------------------------------------------------------------------------
// Gather-aggregate: one wave per node. Lane-parallel CSR preload + shfl
// broadcast removes the dependent index-load from the gather chain.
// ---------------------------------------------------------------------------
__global__ __launch_bounds__(256) void k_agg(const float* __restrict__ H,
                                             const float* __restrict__ dis,
                                             const float* __restrict__ bias,
                                             const int* __restrict__ off,
                                             const int* __restrict__ csr_src,
                                             const float* __restrict__ csr_nrm,
                                             float* __restrict__ AGG) {
    int wid = (blockIdx.x * 256 + threadIdx.x) >> 6;
    if (wid >= N_NODES) return;
    int lane = threadIdx.x & 63;

    const float2* H2 = (const float2*)H;
    float2 b = ((const float2*)bias)[lane];
    float  dn = dis[wid];
    float2 h  = H2[(size_t)wid * 64 + lane];
    float accx = b.x + dn * dn * h.x;
    float accy = b.y + dn * dn * h.y;

    int jb = off[wid];
    int je = off[wid + 1];
    for (int base = jb; base < je; base += 64) {
        int m = je - base;
        if (m > 64) m = 64;
        int   sl = 0;
        float nl = 0.f;
        if (lane < m) {
            sl = csr_src[base + lane];
            nl = csr_nrm[base + lane];
        }
        #pragma unroll 4
        for (int j = 0; j < m; ++j) {
            int   s   = __shfl(sl, j);
            float nrm = __shfl(nl, j);
            float2 v  = H2[(size_t)s * 64 + lane];
            accx += nrm * v.x;
            accy += nrm * v.y;
        }
    }
    ((float2*)AGG)[(size_t)wid * 64 + lane] = make_float2(accx, accy);
}

// ---------------------------------------------------------------------------
// One block (512 thr) per graph: relu + mean-pool (4-way row split) + head
// ---------------------------------------------------------------------------
__global__ __launch_bounds__(512) void k_pool_head(const float* __restrict__ H,
                                                   const int* __restrict__ batch,
                                                   const float* __restrict__ Wl,
                                                   const float* __restrict__ bl,
                                                   float* __restrict__ out) {
    int g   = blockIdx.x;
    int tid = threadIdx.x;
    int f   = tid & 127;
    int q   = tid >> 7;   // 0..3

    int lo = 0, hi = N_NODES;
    while (lo < hi) { int mid = (lo + hi) >> 1; if (batch[mid] < g) lo = mid + 1; else hi = mid; }
    int s = lo;
    lo = s; hi = N_NODES;
    while (lo < hi) { int mid = (lo + hi) >> 1; if (batch[mid] < g + 1) lo = mid + 1; else hi = mid; }
    int e = lo;

    float sum = 0.f;
    for (int i = s + q; i < e; i += 4)
        sum += fmaxf(H[(size_t)i * D + f], 0.f);

    __shared__ float sh[4][128];
    sh[q][f] = sum;
    __syncthreads();

    __shared__ float s0[128];
    __shared__ float s1[128];
    if (tid < 128) {
        float cnt = (float)((e - s) > 0 ? (e - s) : 1);
        float p   = (sh[0][f] + sh[1][f] + sh[2][f] + sh[3][f]) / cnt;
        s0[f] = p * Wl[f * 2 + 0];
        s1[f] = p * Wl[f * 2 + 1];
    }
    __syncthreads();
    #pragma unroll
    for (int o = 64; o > 0; o >>= 1) {
        if (tid < o) { s0[tid] += s0[tid + o]; s1[tid] += s1[tid + o]; }
        __syncthreads();
    }
    if (tid == 0) {
        out[g * 2 + 0] = s0[0] + bl[0];
        out[g * 2 + 1] = s1[0] + bl[1];
    }
}

// ---------------------------------------------------------------------------
extern "C" void kernel_launch(void* const* d_in, const int* in_sizes, int n_in,
                              void* d_out, int out_size, void* d_ws, size_t ws_size,
                              hipStream_t stream) {
    const float* x     = (const float*)d_in[0];
    const int*   ei    = (const int*)  d_in[1];
    const int*   batch = (const int*)  d_in[2];
    const float* W1    = (const float*)d_in[3];
    const float* b1    = (const float*)d_in[4];
    const float* W2    = (const float*)d_in[5];
    const float* b2    = (const float*)d_in[6];
    const float* Wl    = (const float*)d_in[7];
    const float* bl    = (const float*)d_in[8];
    float* out = (float*)d_out;

    char* ws = (char*)d_ws;
    float* bufA       = (float*)(ws);                  // 51.2 MB
    float* bufB       = (float*)(ws + 51200000);       // 51.2 MB
    float* dis        = (float*)(ws + 102400000);      // 400 KB
    int*   cnt        = (int*)  (ws + 102800000);      // 400 KB
    int*   off        = (int*)  (ws + 103200000);      // 400 KB + 16
    int*   pos        = (int*)  (ws + 103600016);      // 400 KB
    int*   chunk_sums = (int*)  (ws + 104000016);      // 800 B
    int*   chunk_offs = (int*)  (ws + 104000816);      // 800 B
    int*   csr_src    = (int*)  (ws + 104001616);      // 2.4 MB
    float* csr_nrm    = (float*)(ws + 106401616);      // 2.4 MB

    const int* srcIdx = ei;
    const int* dstIdx = ei + N_EDGES;

    // ---- CSR build ----
    k_zero2<<<(N_NODES + 255) / 256, 256, 0, stream>>>(cnt, pos);
    k_hist <<<(N_EDGES + 255) / 256, 256, 0, stream>>>(dstIdx, cnt);
    k_scanA<<<NB, CH, 0, stream>>>(cnt, off, chunk_sums, dis);
    k_scanB<<<1,  CH, 0, stream>>>(chunk_sums, chunk_offs, off);
    k_scanC<<<NB, CH, 0, stream>>>(off, chunk_offs);
    k_fill <<<(N_EDGES + 255) / 256, 256, 0, stream>>>(srcIdx, dstIdx, dis, off, pos,
                                                       csr_src, csr_nrm);

    // ---- layer 1 ----
    k_gemm<0><<<(N_NODES + 63) / 64, 512, 0, stream>>>(x, W1, bufA);
    k_agg    <<<(N_NODES * 64 + 255) / 256, 256, 0, stream>>>(bufA, dis, b1, off,
                                                              csr_src, csr_nrm, bufB);
    // ---- layer 2 ----
    k_gemm<1><<<(N_NODES + 63) / 64, 512, 0, stream>>>(bufB, W2, bufA);
    k_agg    <<<(N_NODES * 64 + 255) / 256, 256, 0, stream>>>(bufA, dis, b2, off,
                                                              csr_src, csr_nrm, bufB);
    // ---- relu + mean-pool + head ----
    k_pool_head<<<N_GRAPHS, 512, 0, stream>>>(bufB, batch, Wl, bl, out);
}

// Round 4
// 335.219 us; speedup vs baseline: 7.1345x; 1.2380x over previous
//
#include <hip/hip_runtime.h>
#include <hip/hip_bf16.h>

#define N_NODES  100000
#define N_EDGES  600000
#define D        128
#define N_GRAPHS 512

#define CH   512
#define NB   ((N_NODES + CH - 1) / CH)

typedef __attribute__((ext_vector_type(8))) short      short8v;
typedef __attribute__((ext_vector_type(4))) float      f32x4;

// float -> bf16 (RNE) on raw bits
__device__ __forceinline__ unsigned short f2bf(float f) {
    unsigned int u = __float_as_uint(f);
    u += 0x7fffu + ((u >> 16) & 1u);
    return (unsigned short)(u >> 16);
}
__device__ __forceinline__ float bflo2f(unsigned int p) { return __uint_as_float(p << 16); }
__device__ __forceinline__ float bfhi2f(unsigned int p) { return __uint_as_float(p & 0xffff0000u); }

// ---------------------------------------------------------------------------
__global__ void k_zero2(int* __restrict__ a, int* __restrict__ b) {
    int i = blockIdx.x * blockDim.x + threadIdx.x;
    if (i < N_NODES) { a[i] = 0; b[i] = 0; }
}

__global__ void k_hist(const int* __restrict__ dst, int* __restrict__ cnt) {
    int e = blockIdx.x * blockDim.x + threadIdx.x;
    if (e < N_EDGES) atomicAdd(&cnt[dst[e]], 1);
}

__global__ __launch_bounds__(CH) void k_scanA(const int* __restrict__ cnt,
                                              int* __restrict__ off,
                                              int* __restrict__ chunk_sums,
                                              float* __restrict__ dis) {
    __shared__ int s[CH];
    int tid = threadIdx.x;
    int gid = blockIdx.x * CH + tid;
    int v = (gid < N_NODES) ? cnt[gid] : 0;
    if (gid < N_NODES) dis[gid] = rsqrtf((float)(v + 1));
    s[tid] = v;
    __syncthreads();
    #pragma unroll
    for (int o = 1; o < CH; o <<= 1) {
        int t = (tid >= o) ? s[tid - o] : 0;
        __syncthreads();
        s[tid] += t;
        __syncthreads();
    }
    if (gid < N_NODES) off[gid] = s[tid] - v;
    if (tid == CH - 1) chunk_sums[blockIdx.x] = s[tid];
}

__global__ __launch_bounds__(CH) void k_scanB(const int* __restrict__ chunk_sums,
                                              int* __restrict__ chunk_offs,
                                              int* __restrict__ off) {
    __shared__ int s[CH];
    int tid = threadIdx.x;
    int v = (tid < NB) ? chunk_sums[tid] : 0;
    s[tid] = v;
    __syncthreads();
    #pragma unroll
    for (int o = 1; o < CH; o <<= 1) {
        int t = (tid >= o) ? s[tid - o] : 0;
        __syncthreads();
        s[tid] += t;
        __syncthreads();
    }
    if (tid < NB) chunk_offs[tid] = s[tid] - v;
    if (tid == NB - 1) off[N_NODES] = s[tid];
}

__global__ __launch_bounds__(CH) void k_scanC(int* __restrict__ off,
                                              const int* __restrict__ chunk_offs) {
    int gid = blockIdx.x * CH + threadIdx.x;
    if (gid < N_NODES) off[gid] += chunk_offs[blockIdx.x];
}

__global__ void k_fill(const int* __restrict__ src, const int* __restrict__ dst,
                       const float* __restrict__ dis,
                       const int* __restrict__ off, int* __restrict__ pos,
                       int* __restrict__ csr_src, float* __restrict__ csr_nrm) {
    int e = blockIdx.x * blockDim.x + threadIdx.x;
    if (e >= N_EDGES) return;
    int s = src[e];
    int d = dst[e];
    int j = off[d] + atomicAdd(&pos[d], 1);
    csr_src[j] = s;
    csr_nrm[j] = dis[s] * dis[d];
}

// ---------------------------------------------------------------------------
// Pre-split W[128][128] fp32 into MFMA B-operand fragments (bf16 hi/lo),
// laid out so k_gemm_mfma can ds_read_b128 them directly:
//   frag index t = kc*512 + cb*64 + lane ; element j (0..7):
//   value = W[kc*32 + (lane>>4)*8 + j][cb*16 + (lane&15)]
// ---------------------------------------------------------------------------
__global__ void k_wsplit(const float* __restrict__ W,
                         unsigned short* __restrict__ whi,
                         unsigned short* __restrict__ wlo) {
    int t = blockIdx.x * 256 + threadIdx.x;
    if (t >= 2048) return;
    int lane = t & 63;
    int cb   = (t >> 6) & 7;
    int kc   = t >> 9;
    int krow = kc * 32 + ((lane >> 4) * 8);
    int col  = cb * 16 + (lane & 15);

    unsigned short h8[8], l8[8];
    #pragma unroll
    for (int j = 0; j < 8; ++j) {
        float f = W[(krow + j) * D + col];
        unsigned short h = f2bf(f);
        float hf = __uint_as_float(((unsigned int)h) << 16);
        h8[j] = h;
        l8[j] = f2bf(f - hf);
    }
    #pragma unroll
    for (int j = 0; j < 8; ++j) { whi[t * 8 + j] = h8[j]; wlo[t * 8 + j] = l8[j]; }
}

// ---------------------------------------------------------------------------
// Y[bf16] = (RELU_IN ? relu(X) : X) @ W  via 16x16x32 bf16 MFMA.
// Block: 256 thr (4 waves), 128 rows; wave owns 32 rows x 128 cols.
// Operands swapped (w_frag first) -> D holds Y^T tiles -> each lane stores
// 4 consecutive Y columns as one 8-B packed write.
// SPLIT_X: 1 = fp32 input, split into hi+lo (3 MFMAs); 0 = bf16 input (2 MFMAs).
// ---------------------------------------------------------------------------
template<int RELU_IN, int SPLIT_X>
__global__ __launch_bounds__(256) void k_gemm_mfma(const void* __restrict__ Xv,
                                                   const unsigned short* __restrict__ whi,
                                                   const unsigned short* __restrict__ wlo,
                                                   unsigned short* __restrict__ Y) {
    __shared__ short wl_hi[16384];   // 32 KB
    __shared__ short wl_lo[16384];   // 32 KB

    const int tid = threadIdx.x;

    // stage W fragments (linear copy)
    {
        const float4* sh = (const float4*)whi;
        const float4* sl = (const float4*)wlo;
        float4* dh = (float4*)wl_hi;
        float4* dl = (float4*)wl_lo;
        #pragma unroll
        for (int i = tid; i < 2048; i += 256) { dh[i] = sh[i]; dl[i] = sl[i]; }
    }
    __syncthreads();

    const int wave = tid >> 6;
    const int lane = tid & 63;
    const int lrow = lane & 15;
    const int kgrp = lane >> 4;          // 0..3
    const int row_base = blockIdx.x * 128 + wave * 32;

    const float*          Xf = (const float*)Xv;
    const unsigned short* Xb = (const unsigned short*)Xv;

    f32x4 acc[2][8];
    #pragma unroll
    for (int rg = 0; rg < 2; ++rg)
        #pragma unroll
        for (int cb = 0; cb < 8; ++cb)
            acc[rg][cb] = (f32x4){0.f, 0.f, 0.f, 0.f};

    #pragma unroll
    for (int kc = 0; kc < 4; ++kc) {
        const int kof = kc * 32 + kgrp * 8;

        short8v xh[2], xl[2];
        #pragma unroll
        for (int rg = 0; rg < 2; ++rg) {
            const int row = row_base + rg * 16 + lrow;
            if (SPLIT_X) {
                float fv[8];
                if (row < N_NODES) {
                    const float* p = Xf + (size_t)row * D + kof;
                    float4 a = *(const float4*)p;
                    float4 b = *(const float4*)(p + 4);
                    fv[0] = a.x; fv[1] = a.y; fv[2] = a.z; fv[3] = a.w;
                    fv[4] = b.x; fv[5] = b.y; fv[6] = b.z; fv[7] = b.w;
                } else {
                    #pragma unroll
                    for (int j = 0; j < 8; ++j) fv[j] = 0.f;
                }
                #pragma unroll
                for (int j = 0; j < 8; ++j) {
                    float f = RELU_IN ? fmaxf(fv[j], 0.f) : fv[j];
                    unsigned short h = f2bf(f);
                    float hf = __uint_as_float(((unsigned int)h) << 16);
                    xh[rg][j] = (short)h;
                    xl[rg][j] = (short)f2bf(f - hf);
                }
            } else {
                short8v v = {0, 0, 0, 0, 0, 0, 0, 0};
                if (row < N_NODES)
                    v = *(const short8v*)(Xb + (size_t)row * D + kof);
                if (RELU_IN) {
                    #pragma unroll
                    for (int j = 0; j < 8; ++j)
                        if (((unsigned short)v[j]) & 0x8000u) v[j] = 0;
                }
                xh[rg] = v;
            }
        }

        #pragma unroll
        for (int cb = 0; cb < 8; ++cb) {
            const int fo = ((kc * 8 + cb) * 64 + lane) * 8;
            short8v bh = *(const short8v*)&wl_hi[fo];
            short8v bl = *(const short8v*)&wl_lo[fo];
            #pragma unroll
            for (int rg = 0; rg < 2; ++rg) {
                acc[rg][cb] = __builtin_amdgcn_mfma_f32_16x16x32_bf16(bh, xh[rg], acc[rg][cb], 0, 0, 0);
                acc[rg][cb] = __builtin_amdgcn_mfma_f32_16x16x32_bf16(bl, xh[rg], acc[rg][cb], 0, 0, 0);
                if (SPLIT_X)
                    acc[rg][cb] = __builtin_amdgcn_mfma_f32_16x16x32_bf16(bh, xl[rg], acc[rg][cb], 0, 0, 0);
            }
        }
    }

    // epilogue: lane holds Y[row_base+rg*16+lrow][cb*16 + kgrp*4 + r], r=0..3
    #pragma unroll
    for (int rg = 0; rg < 2; ++rg) {
        const int row = row_base + rg * 16 + lrow;
        if (row >= N_NODES) continue;
        #pragma unroll
        for (int cb = 0; cb < 8; ++cb) {
            f32x4 a = acc[rg][cb];
            unsigned int p0 = (unsigned int)f2bf(a[0]) | ((unsigned int)f2bf(a[1]) << 16);
            unsigned int p1 = (unsigned int)f2bf(a[2]) | ((unsigned int)f2bf(a[3]) << 16);
            uint2 pv; pv.x = p0; pv.y = p1;
            *(uint2*)(Y + (size_t)row * D + cb * 16 + kgrp * 4) = pv;
        }
    }
}

// ---------------------------------------------------------------------------
// Gather-aggregate on bf16 H: one wave per node, 2 cols (1 dword) per lane.
// AGG[n,:] = bf16( bias + dis[n]^2*H[n,:] + sum_j nrm[j]*H[src[j],:] )
// ---------------------------------------------------------------------------
__global__ __launch_bounds__(256) void k_agg(const unsigned int* __restrict__ Hb,
                                             const float* __restrict__ dis,
                                             const float* __restrict__ bias,
                                             const int* __restrict__ off,
                                             const int* __restrict__ csr_src,
                                             const float* __restrict__ csr_nrm,
                                             unsigned int* __restrict__ AGGb) {
    int wid = (blockIdx.x * 256 + threadIdx.x) >> 6;
    if (wid >= N_NODES) return;
    int lane = threadIdx.x & 63;

    float2 b = ((const float2*)bias)[lane];
    float dn = dis[wid];
    float dn2 = dn * dn;
    unsigned int self = Hb[(size_t)wid * 64 + lane];
    float accx = b.x + dn2 * bflo2f(self);
    float accy = b.y + dn2 * bfhi2f(self);

    int jb = off[wid];
    int je = off[wid + 1];
    for (int base = jb; base < je; base += 64) {
        int m = je - base;
        if (m > 64) m = 64;
        int   sl = 0;
        float nl = 0.f;
        if (lane < m) {
            sl = csr_src[base + lane];
            nl = csr_nrm[base + lane];
        }
        #pragma unroll 4
        for (int j = 0; j < m; ++j) {
            int   s   = __shfl(sl, j);
            float nrm = __shfl(nl, j);
            unsigned int v = Hb[(size_t)s * 64 + lane];
            accx += nrm * bflo2f(v);
            accy += nrm * bfhi2f(v);
        }
    }
    unsigned int o = (unsigned int)f2bf(accx) | (((unsigned int)f2bf(accy)) << 16);
    AGGb[(size_t)wid * 64 + lane] = o;
}

// ---------------------------------------------------------------------------
// One block (512 thr) per graph: relu + mean-pool (bf16 in) + linear head
// ---------------------------------------------------------------------------
__global__ __launch_bounds__(512) void k_pool_head(const unsigned short* __restrict__ Hb,
                                                   const int* __restrict__ batch,
                                                   const float* __restrict__ Wl,
                                                   const float* __restrict__ bl,
                                                   float* __restrict__ out) {
    int g   = blockIdx.x;
    int tid = threadIdx.x;
    int f   = tid & 127;
    int q   = tid >> 7;

    int lo = 0, hi = N_NODES;
    while (lo < hi) { int mid = (lo + hi) >> 1; if (batch[mid] < g) lo = mid + 1; else hi = mid; }
    int s = lo;
    lo = s; hi = N_NODES;
    while (lo < hi) { int mid = (lo + hi) >> 1; if (batch[mid] < g + 1) lo = mid + 1; else hi = mid; }
    int e = lo;

    float sum = 0.f;
    for (int i = s + q; i < e; i += 4) {
        float v = __uint_as_float(((unsigned int)Hb[(size_t)i * D + f]) << 16);
        sum += fmaxf(v, 0.f);
    }

    __shared__ float sh[4][128];
    sh[q][f] = sum;
    __syncthreads();

    __shared__ float s0[128];
    __shared__ float s1[128];
    if (tid < 128) {
        float cnt = (float)((e - s) > 0 ? (e - s) : 1);
        float p   = (sh[0][f] + sh[1][f] + sh[2][f] + sh[3][f]) / cnt;
        s0[f] = p * Wl[f * 2 + 0];
        s1[f] = p * Wl[f * 2 + 1];
    }
    __syncthreads();
    #pragma unroll
    for (int o = 64; o > 0; o >>= 1) {
        if (tid < o) { s0[tid] += s0[tid + o]; s1[tid] += s1[tid + o]; }
        __syncthreads();
    }
    if (tid == 0) {
        out[g * 2 + 0] = s0[0] + bl[0];
        out[g * 2 + 1] = s1[0] + bl[1];
    }
}

// ---------------------------------------------------------------------------
extern "C" void kernel_launch(void* const* d_in, const int* in_sizes, int n_in,
                              void* d_out, int out_size, void* d_ws, size_t ws_size,
                              hipStream_t stream) {
    const float* x     = (const float*)d_in[0];
    const int*   ei    = (const int*)  d_in[1];
    const int*   batch = (const int*)  d_in[2];
    const float* W1    = (const float*)d_in[3];
    const float* b1    = (const float*)d_in[4];
    const float* W2    = (const float*)d_in[5];
    const float* b2    = (const float*)d_in[6];
    const float* Wl    = (const float*)d_in[7];
    const float* bl    = (const float*)d_in[8];
    float* out = (float*)d_out;

    char* ws = (char*)d_ws;
    unsigned short* HbA = (unsigned short*)(ws);               // 25.6 MB bf16
    unsigned short* HbB = (unsigned short*)(ws + 25600000);    // 25.6 MB bf16
    float* dis        = (float*)(ws + 51200000);               // 400 KB
    int*   cnt        = (int*)  (ws + 51600000);               // 400 KB
    int*   off        = (int*)  (ws + 52000000);               // 400 KB + 16
    int*   pos        = (int*)  (ws + 52400016);               // 400 KB
    int*   chunk_sums = (int*)  (ws + 52800016);               // 1 KB
    int*   chunk_offs = (int*)  (ws + 52801040);               // 1 KB
    int*   csr_src    = (int*)  (ws + 52802064);               // 2.4 MB
    float* csr_nrm    = (float*)(ws + 55202064);               // 2.4 MB
    unsigned short* whi1 = (unsigned short*)(ws + 57602064);   // 32 KB
    unsigned short* wlo1 = (unsigned short*)(ws + 57634832);   // 32 KB
    unsigned short* whi2 = (unsigned short*)(ws + 57667600);   // 32 KB
    unsigned short* wlo2 = (unsigned short*)(ws + 57700368);   // 32 KB

    const int* srcIdx = ei;
    const int* dstIdx = ei + N_EDGES;

    // ---- W pre-split (independent of CSR) ----
    k_wsplit<<<8, 256, 0, stream>>>(W1, whi1, wlo1);
    k_wsplit<<<8, 256, 0, stream>>>(W2, whi2, wlo2);

    // ---- CSR build ----
    k_zero2<<<(N_NODES + 255) / 256, 256, 0, stream>>>(cnt, pos);
    k_hist <<<(N_EDGES + 255) / 256, 256, 0, stream>>>(dstIdx, cnt);
    k_scanA<<<NB, CH, 0, stream>>>(cnt, off, chunk_sums, dis);
    k_scanB<<<1,  CH, 0, stream>>>(chunk_sums, chunk_offs, off);
    k_scanC<<<NB, CH, 0, stream>>>(off, chunk_offs);
    k_fill <<<(N_EDGES + 255) / 256, 256, 0, stream>>>(srcIdx, dstIdx, dis, off, pos,
                                                       csr_src, csr_nrm);

    const int gemm_grid = (N_NODES + 127) / 128;
    const int agg_grid  = (N_NODES * 64 + 255) / 256;

    // ---- layer 1 ----
    k_gemm_mfma<0, 1><<<gemm_grid, 256, 0, stream>>>(x, whi1, wlo1, HbA);
    k_agg<<<agg_grid, 256, 0, stream>>>((const unsigned int*)HbA, dis, b1, off,
                                        csr_src, csr_nrm, (unsigned int*)HbB);
    // ---- layer 2 (relu fused into GEMM input) ----
    k_gemm_mfma<1, 0><<<gemm_grid, 256, 0, stream>>>(HbB, whi2, wlo2, HbA);
    k_agg<<<agg_grid, 256, 0, stream>>>((const unsigned int*)HbA, dis, b2, off,
                                        csr_src, csr_nrm, (unsigned int*)HbB);
    // ---- relu + mean-pool + head ----
    k_pool_head<<<N_GRAPHS, 512, 0, stream>>>(HbB, batch, Wl, bl, out);
}

// Round 5
// 296.185 us; speedup vs baseline: 8.0748x; 1.1318x over previous
//
#include <hip/hip_runtime.h>
#include <hip/hip_bf16.h>

#define N_NODES  100000
#define N_EDGES  600000
#define D        128
#define N_GRAPHS 512

#define CH   512
#define NB   ((N_NODES + CH - 1) / CH)

typedef __attribute__((ext_vector_type(8))) short      short8v;
typedef __attribute__((ext_vector_type(4))) float      f32x4;

// float -> bf16 (RNE) on raw bits
__device__ __forceinline__ unsigned short f2bf(float f) {
    unsigned int u = __float_as_uint(f);
    u += 0x7fffu + ((u >> 16) & 1u);
    return (unsigned short)(u >> 16);
}
__device__ __forceinline__ float bflo2f(unsigned int p) { return __uint_as_float(p << 16); }
__device__ __forceinline__ float bfhi2f(unsigned int p) { return __uint_as_float(p & 0xffff0000u); }

// ---------------------------------------------------------------------------
__global__ void k_zero2(int* __restrict__ a, int* __restrict__ b) {
    int i = blockIdx.x * blockDim.x + threadIdx.x;
    if (i < N_NODES) { a[i] = 0; b[i] = 0; }
}

__global__ void k_hist(const int* __restrict__ dst, int* __restrict__ cnt) {
    int e = blockIdx.x * blockDim.x + threadIdx.x;
    if (e < N_EDGES) atomicAdd(&cnt[dst[e]], 1);
}

__global__ __launch_bounds__(CH) void k_scanA(const int* __restrict__ cnt,
                                              int* __restrict__ off,
                                              int* __restrict__ chunk_sums,
                                              float* __restrict__ dis) {
    __shared__ int s[CH];
    int tid = threadIdx.x;
    int gid = blockIdx.x * CH + tid;
    int v = (gid < N_NODES) ? cnt[gid] : 0;
    if (gid < N_NODES) dis[gid] = rsqrtf((float)(v + 1));
    s[tid] = v;
    __syncthreads();
    #pragma unroll
    for (int o = 1; o < CH; o <<= 1) {
        int t = (tid >= o) ? s[tid - o] : 0;
        __syncthreads();
        s[tid] += t;
        __syncthreads();
    }
    if (gid < N_NODES) off[gid] = s[tid] - v;
    if (tid == CH - 1) chunk_sums[blockIdx.x] = s[tid];
}

__global__ __launch_bounds__(CH) void k_scanB(const int* __restrict__ chunk_sums,
                                              int* __restrict__ chunk_offs,
                                              int* __restrict__ off) {
    __shared__ int s[CH];
    int tid = threadIdx.x;
    int v = (tid < NB) ? chunk_sums[tid] : 0;
    s[tid] = v;
    __syncthreads();
    #pragma unroll
    for (int o = 1; o < CH; o <<= 1) {
        int t = (tid >= o) ? s[tid - o] : 0;
        __syncthreads();
        s[tid] += t;
        __syncthreads();
    }
    if (tid < NB) chunk_offs[tid] = s[tid] - v;
    if (tid == NB - 1) off[N_NODES] = s[tid];
}

__global__ __launch_bounds__(CH) void k_scanC(int* __restrict__ off,
                                              const int* __restrict__ chunk_offs) {
    int gid = blockIdx.x * CH + threadIdx.x;
    if (gid < N_NODES) off[gid] += chunk_offs[blockIdx.x];
}

__global__ void k_fill(const int* __restrict__ src, const int* __restrict__ dst,
                       const float* __restrict__ dis,
                       const int* __restrict__ off, int* __restrict__ pos,
                       int* __restrict__ csr_src, float* __restrict__ csr_nrm) {
    int e = blockIdx.x * blockDim.x + threadIdx.x;
    if (e >= N_EDGES) return;
    int s = src[e];
    int d = dst[e];
    int j = off[d] + atomicAdd(&pos[d], 1);
    csr_src[j] = s;
    csr_nrm[j] = dis[s] * dis[d];
}

// ---------------------------------------------------------------------------
// Pre-split W1 and W2 [128][128] fp32 into MFMA B-operand fragments (bf16
// hi/lo), fragment order matches k_gemm_mfma's ds_read_b128 layout.
// ---------------------------------------------------------------------------
__global__ void k_wsplit2(const float* __restrict__ W1, const float* __restrict__ W2,
                          unsigned short* __restrict__ whi1, unsigned short* __restrict__ wlo1,
                          unsigned short* __restrict__ whi2, unsigned short* __restrict__ wlo2) {
    int tt = blockIdx.x * 256 + threadIdx.x;
    if (tt >= 4096) return;
    const float* W = (tt < 2048) ? W1 : W2;
    unsigned short* whi = (tt < 2048) ? whi1 : whi2;
    unsigned short* wlo = (tt < 2048) ? wlo1 : wlo2;
    int t = tt & 2047;

    int lane = t & 63;
    int cb   = (t >> 6) & 7;
    int kc   = t >> 9;
    int krow = kc * 32 + ((lane >> 4) * 8);
    int col  = cb * 16 + (lane & 15);

    unsigned short h8[8], l8[8];
    #pragma unroll
    for (int j = 0; j < 8; ++j) {
        float f = W[(krow + j) * D + col];
        unsigned short h = f2bf(f);
        float hf = __uint_as_float(((unsigned int)h) << 16);
        h8[j] = h;
        l8[j] = f2bf(f - hf);
    }
    #pragma unroll
    for (int j = 0; j < 8; ++j) { whi[t * 8 + j] = h8[j]; wlo[t * 8 + j] = l8[j]; }
}

// ---------------------------------------------------------------------------
// Y[bf16] = (RELU_IN ? relu(X) : X) @ W  via 16x16x32 bf16 MFMA.
// (unchanged from R4 — off the critical path)
// ---------------------------------------------------------------------------
template<int RELU_IN, int SPLIT_X>
__global__ __launch_bounds__(256) void k_gemm_mfma(const void* __restrict__ Xv,
                                                   const unsigned short* __restrict__ whi,
                                                   const unsigned short* __restrict__ wlo,
                                                   unsigned short* __restrict__ Y) {
    __shared__ short wl_hi[16384];
    __shared__ short wl_lo[16384];

    const int tid = threadIdx.x;

    {
        const float4* sh = (const float4*)whi;
        const float4* sl = (const float4*)wlo;
        float4* dh = (float4*)wl_hi;
        float4* dl = (float4*)wl_lo;
        #pragma unroll
        for (int i = tid; i < 2048; i += 256) { dh[i] = sh[i]; dl[i] = sl[i]; }
    }
    __syncthreads();

    const int wave = tid >> 6;
    const int lane = tid & 63;
    const int lrow = lane & 15;
    const int kgrp = lane >> 4;
    const int row_base = blockIdx.x * 128 + wave * 32;

    const float*          Xf = (const float*)Xv;
    const unsigned short* Xb = (const unsigned short*)Xv;

    f32x4 acc[2][8];
    #pragma unroll
    for (int rg = 0; rg < 2; ++rg)
        #pragma unroll
        for (int cb = 0; cb < 8; ++cb)
            acc[rg][cb] = (f32x4){0.f, 0.f, 0.f, 0.f};

    #pragma unroll
    for (int kc = 0; kc < 4; ++kc) {
        const int kof = kc * 32 + kgrp * 8;

        short8v xh[2], xl[2];
        #pragma unroll
        for (int rg = 0; rg < 2; ++rg) {
            const int row = row_base + rg * 16 + lrow;
            if (SPLIT_X) {
                float fv[8];
                if (row < N_NODES) {
                    const float* p = Xf + (size_t)row * D + kof;
                    float4 a = *(const float4*)p;
                    float4 b = *(const float4*)(p + 4);
                    fv[0] = a.x; fv[1] = a.y; fv[2] = a.z; fv[3] = a.w;
                    fv[4] = b.x; fv[5] = b.y; fv[6] = b.z; fv[7] = b.w;
                } else {
                    #pragma unroll
                    for (int j = 0; j < 8; ++j) fv[j] = 0.f;
                }
                #pragma unroll
                for (int j = 0; j < 8; ++j) {
                    float f = RELU_IN ? fmaxf(fv[j], 0.f) : fv[j];
                    unsigned short h = f2bf(f);
                    float hf = __uint_as_float(((unsigned int)h) << 16);
                    xh[rg][j] = (short)h;
                    xl[rg][j] = (short)f2bf(f - hf);
                }
            } else {
                short8v v = {0, 0, 0, 0, 0, 0, 0, 0};
                if (row < N_NODES)
                    v = *(const short8v*)(Xb + (size_t)row * D + kof);
                if (RELU_IN) {
                    #pragma unroll
                    for (int j = 0; j < 8; ++j)
                        if (((unsigned short)v[j]) & 0x8000u) v[j] = 0;
                }
                xh[rg] = v;
            }
        }

        #pragma unroll
        for (int cb = 0; cb < 8; ++cb) {
            const int fo = ((kc * 8 + cb) * 64 + lane) * 8;
            short8v bh = *(const short8v*)&wl_hi[fo];
            short8v bl = *(const short8v*)&wl_lo[fo];
            #pragma unroll
            for (int rg = 0; rg < 2; ++rg) {
                acc[rg][cb] = __builtin_amdgcn_mfma_f32_16x16x32_bf16(bh, xh[rg], acc[rg][cb], 0, 0, 0);
                acc[rg][cb] = __builtin_amdgcn_mfma_f32_16x16x32_bf16(bl, xh[rg], acc[rg][cb], 0, 0, 0);
                if (SPLIT_X)
                    acc[rg][cb] = __builtin_amdgcn_mfma_f32_16x16x32_bf16(bh, xl[rg], acc[rg][cb], 0, 0, 0);
            }
        }
    }

    #pragma unroll
    for (int rg = 0; rg < 2; ++rg) {
        const int row = row_base + rg * 16 + lrow;
        if (row >= N_NODES) continue;
        #pragma unroll
        for (int cb = 0; cb < 8; ++cb) {
            f32x4 a = acc[rg][cb];
            unsigned int p0 = (unsigned int)f2bf(a[0]) | ((unsigned int)f2bf(a[1]) << 16);
            unsigned int p1 = (unsigned int)f2bf(a[2]) | ((unsigned int)f2bf(a[3]) << 16);
            uint2 pv; pv.x = p0; pv.y = p1;
            *(uint2*)(Y + (size_t)row * D + cb * 16 + kgrp * 4) = pv;
        }
    }
}

// ---------------------------------------------------------------------------
// Gather-aggregate v3: one wave per node. CSR entries read as WAVE-UNIFORM
// scalars (readfirstlane -> s_load, zero bpermutes); gathers issued 8-deep
// with clamp-to-last-edge + nrm=0 masking (no padding, no branches).
// ---------------------------------------------------------------------------
__global__ __launch_bounds__(256) void k_agg(const unsigned int* __restrict__ Hb,
                                             const float* __restrict__ dis,
                                             const float* __restrict__ bias,
                                             const int* __restrict__ off,
                                             const int* __restrict__ csr_src,
                                             const float* __restrict__ csr_nrm,
                                             unsigned int* __restrict__ AGGb) {
    int wid = (blockIdx.x * 256 + threadIdx.x) >> 6;
    if (wid >= N_NODES) return;
    int lane = threadIdx.x & 63;

    int jb = __builtin_amdgcn_readfirstlane(off[wid]);
    int je = __builtin_amdgcn_readfirstlane(off[wid + 1]);

    float2 b = ((const float2*)bias)[lane];
    float dn = dis[wid];
    float dn2 = dn * dn;
    unsigned int self = Hb[(size_t)wid * 64 + lane];
    float accx = b.x + dn2 * bflo2f(self);
    float accy = b.y + dn2 * bfhi2f(self);

    for (int base = jb; base < je; base += 8) {
        int   si[8];
        float ni[8];
        #pragma unroll
        for (int i = 0; i < 8; ++i) {
            int j = base + i;
            int jc = (j < je) ? j : (je - 1);     // clamped: always a valid edge
            si[i] = csr_src[jc];                  // uniform -> s_load
            float n = csr_nrm[jc];                // uniform -> s_load
            ni[i] = (j < je) ? n : 0.f;
        }
        unsigned int v[8];
        #pragma unroll
        for (int i = 0; i < 8; ++i)
            v[i] = Hb[(size_t)si[i] * 64 + lane]; // 8 loads in flight
        #pragma unroll
        for (int i = 0; i < 8; ++i) {
            accx += ni[i] * bflo2f(v[i]);
            accy += ni[i] * bfhi2f(v[i]);
        }
    }
    unsigned int o = (unsigned int)f2bf(accx) | (((unsigned int)f2bf(accy)) << 16);
    AGGb[(size_t)wid * 64 + lane] = o;
}

// ---------------------------------------------------------------------------
// One block (512 thr) per graph: relu + mean-pool (bf16 in) + linear head
// ---------------------------------------------------------------------------
__global__ __launch_bounds__(512) void k_pool_head(const unsigned short* __restrict__ Hb,
                                                   const int* __restrict__ batch,
                                                   const float* __restrict__ Wl,
                                                   const float* __restrict__ bl,
                                                   float* __restrict__ out) {
    int g   = blockIdx.x;
    int tid = threadIdx.x;
    int f   = tid & 127;
    int q   = tid >> 7;

    int lo = 0, hi = N_NODES;
    while (lo < hi) { int mid = (lo + hi) >> 1; if (batch[mid] < g) lo = mid + 1; else hi = mid; }
    int s = lo;
    lo = s; hi = N_NODES;
    while (lo < hi) { int mid = (lo + hi) >> 1; if (batch[mid] < g + 1) lo = mid + 1; else hi = mid; }
    int e = lo;

    float sum = 0.f;
    for (int i = s + q; i < e; i += 4) {
        float v = __uint_as_float(((unsigned int)Hb[(size_t)i * D + f]) << 16);
        sum += fmaxf(v, 0.f);
    }

    __shared__ float sh[4][128];
    sh[q][f] = sum;
    __syncthreads();

    __shared__ float s0[128];
    __shared__ float s1[128];
    if (tid < 128) {
        float cnt = (float)((e - s) > 0 ? (e - s) : 1);
        float p   = (sh[0][f] + sh[1][f] + sh[2][f] + sh[3][f]) / cnt;
        s0[f] = p * Wl[f * 2 + 0];
        s1[f] = p * Wl[f * 2 + 1];
    }
    __syncthreads();
    #pragma unroll
    for (int o = 64; o > 0; o >>= 1) {
        if (tid < o) { s0[tid] += s0[tid + o]; s1[tid] += s1[tid + o]; }
        __syncthreads();
    }
    if (tid == 0) {
        out[g * 2 + 0] = s0[0] + bl[0];
        out[g * 2 + 1] = s1[0] + bl[1];
    }
}

// ---------------------------------------------------------------------------
extern "C" void kernel_launch(void* const* d_in, const int* in_sizes, int n_in,
                              void* d_out, int out_size, void* d_ws, size_t ws_size,
                              hipStream_t stream) {
    const float* x     = (const float*)d_in[0];
    const int*   ei    = (const int*)  d_in[1];
    const int*   batch = (const int*)  d_in[2];
    const float* W1    = (const float*)d_in[3];
    const float* b1    = (const float*)d_in[4];
    const float* W2    = (const float*)d_in[5];
    const float* b2    = (const float*)d_in[6];
    const float* Wl    = (const float*)d_in[7];
    const float* bl    = (const float*)d_in[8];
    float* out = (float*)d_out;

    char* ws = (char*)d_ws;
    unsigned short* HbA = (unsigned short*)(ws);               // 25.6 MB bf16
    unsigned short* HbB = (unsigned short*)(ws + 25600000);    // 25.6 MB bf16
    float* dis        = (float*)(ws + 51200000);               // 400 KB
    int*   cnt        = (int*)  (ws + 51600000);               // 400 KB
    int*   off        = (int*)  (ws + 52000000);               // 400 KB + 16
    int*   pos        = (int*)  (ws + 52400016);               // 400 KB
    int*   chunk_sums = (int*)  (ws + 52800016);               // 1 KB
    int*   chunk_offs = (int*)  (ws + 52801040);               // 1 KB
    int*   csr_src    = (int*)  (ws + 52802064);               // 2.4 MB
    float* csr_nrm    = (float*)(ws + 55202064);               // 2.4 MB
    unsigned short* whi1 = (unsigned short*)(ws + 57602064);   // 32 KB
    unsigned short* wlo1 = (unsigned short*)(ws + 57634832);   // 32 KB
    unsigned short* whi2 = (unsigned short*)(ws + 57667600);   // 32 KB
    unsigned short* wlo2 = (unsigned short*)(ws + 57700368);   // 32 KB

    const int* srcIdx = ei;
    const int* dstIdx = ei + N_EDGES;

    // ---- W pre-split (both layers, one launch) ----
    k_wsplit2<<<16, 256, 0, stream>>>(W1, W2, whi1, wlo1, whi2, wlo2);

    // ---- CSR build ----
    k_zero2<<<(N_NODES + 255) / 256, 256, 0, stream>>>(cnt, pos);
    k_hist <<<(N_EDGES + 255) / 256, 256, 0, stream>>>(dstIdx, cnt);
    k_scanA<<<NB, CH, 0, stream>>>(cnt, off, chunk_sums, dis);
    k_scanB<<<1,  CH, 0, stream>>>(chunk_sums, chunk_offs, off);
    k_scanC<<<NB, CH, 0, stream>>>(off, chunk_offs);
    k_fill <<<(N_EDGES + 255) / 256, 256, 0, stream>>>(srcIdx, dstIdx, dis, off, pos,
                                                       csr_src, csr_nrm);

    const int gemm_grid = (N_NODES + 127) / 128;
    const int agg_grid  = (N_NODES * 64 + 255) / 256;

    // ---- layer 1 ----
    k_gemm_mfma<0, 1><<<gemm_grid, 256, 0, stream>>>(x, whi1, wlo1, HbA);
    k_agg<<<agg_grid, 256, 0, stream>>>((const unsigned int*)HbA, dis, b1, off,
                                        csr_src, csr_nrm, (unsigned int*)HbB);
    // ---- layer 2 (relu fused into GEMM input) ----
    k_gemm_mfma<1, 0><<<gemm_grid, 256, 0, stream>>>(HbB, whi2, wlo2, HbA);
    k_agg<<<agg_grid, 256, 0, stream>>>((const unsigned int*)HbA, dis, b2, off,
                                        csr_src, csr_nrm, (unsigned int*)HbB);
    // ---- relu + mean-pool + head ----
    k_pool_head<<<N_GRAPHS, 512, 0, stream>>>(HbB, batch, Wl, bl, out);
}

// Round 6
// 293.449 us; speedup vs baseline: 8.1501x; 1.0093x over previous
//
#include <hip/hip_runtime.h>
#include <hip/hip_bf16.h>

#define N_NODES  100000
#define N_EDGES  600000
#define D        128
#define N_GRAPHS 512

#define CH   512
#define NB   ((N_NODES + CH - 1) / CH)

typedef __attribute__((ext_vector_type(8))) short      short8v;
typedef __attribute__((ext_vector_type(4))) float      f32x4;

// float -> bf16 (RNE) on raw bits
__device__ __forceinline__ unsigned short f2bf(float f) {
    unsigned int u = __float_as_uint(f);
    u += 0x7fffu + ((u >> 16) & 1u);
    return (unsigned short)(u >> 16);
}
__device__ __forceinline__ float bflo2f(unsigned int p) { return __uint_as_float(p << 16); }
__device__ __forceinline__ float bfhi2f(unsigned int p) { return __uint_as_float(p & 0xffff0000u); }

// ---------------------------------------------------------------------------
__global__ void k_zero2(int* __restrict__ a, int* __restrict__ b) {
    int i = blockIdx.x * blockDim.x + threadIdx.x;
    if (i < N_NODES) { a[i] = 0; b[i] = 0; }
}

__global__ void k_hist(const int* __restrict__ dst, int* __restrict__ cnt) {
    int e = blockIdx.x * blockDim.x + threadIdx.x;
    if (e < N_EDGES) atomicAdd(&cnt[dst[e]], 1);
}

__global__ __launch_bounds__(CH) void k_scanA(const int* __restrict__ cnt,
                                              int* __restrict__ off,
                                              int* __restrict__ chunk_sums,
                                              float* __restrict__ dis) {
    __shared__ int s[CH];
    int tid = threadIdx.x;
    int gid = blockIdx.x * CH + tid;
    int v = (gid < N_NODES) ? cnt[gid] : 0;
    if (gid < N_NODES) dis[gid] = rsqrtf((float)(v + 1));
    s[tid] = v;
    __syncthreads();
    #pragma unroll
    for (int o = 1; o < CH; o <<= 1) {
        int t = (tid >= o) ? s[tid - o] : 0;
        __syncthreads();
        s[tid] += t;
        __syncthreads();
    }
    if (gid < N_NODES) off[gid] = s[tid] - v;
    if (tid == CH - 1) chunk_sums[blockIdx.x] = s[tid];
}

__global__ __launch_bounds__(CH) void k_scanB(const int* __restrict__ chunk_sums,
                                              int* __restrict__ chunk_offs,
                                              int* __restrict__ off) {
    __shared__ int s[CH];
    int tid = threadIdx.x;
    int v = (tid < NB) ? chunk_sums[tid] : 0;
    s[tid] = v;
    __syncthreads();
    #pragma unroll
    for (int o = 1; o < CH; o <<= 1) {
        int t = (tid >= o) ? s[tid - o] : 0;
        __syncthreads();
        s[tid] += t;
        __syncthreads();
    }
    if (tid < NB) chunk_offs[tid] = s[tid] - v;
    if (tid == NB - 1) off[N_NODES] = s[tid];
}

__global__ __launch_bounds__(CH) void k_scanC(int* __restrict__ off,
                                              const int* __restrict__ chunk_offs) {
    int gid = blockIdx.x * CH + threadIdx.x;
    if (gid < N_NODES) off[gid] += chunk_offs[blockIdx.x];
}

__global__ void k_fill(const int* __restrict__ src, const int* __restrict__ dst,
                       const float* __restrict__ dis,
                       const int* __restrict__ off, int* __restrict__ pos,
                       int* __restrict__ csr_src, float* __restrict__ csr_nrm) {
    int e = blockIdx.x * blockDim.x + threadIdx.x;
    if (e >= N_EDGES) return;
    int s = src[e];
    int d = dst[e];
    int j = off[d] + atomicAdd(&pos[d], 1);
    csr_src[j] = s;
    csr_nrm[j] = dis[s] * dis[d];
}

// ---------------------------------------------------------------------------
// Pre-split W1 and W2 [128][128] fp32 into MFMA B-operand fragments (bf16
// hi/lo), fragment order matches k_gemm_mfma's ds_read_b128 layout.
// ---------------------------------------------------------------------------
__global__ void k_wsplit2(const float* __restrict__ W1, const float* __restrict__ W2,
                          unsigned short* __restrict__ whi1, unsigned short* __restrict__ wlo1,
                          unsigned short* __restrict__ whi2, unsigned short* __restrict__ wlo2) {
    int tt = blockIdx.x * 256 + threadIdx.x;
    if (tt >= 4096) return;
    const float* W = (tt < 2048) ? W1 : W2;
    unsigned short* whi = (tt < 2048) ? whi1 : whi2;
    unsigned short* wlo = (tt < 2048) ? wlo1 : wlo2;
    int t = tt & 2047;

    int lane = t & 63;
    int cb   = (t >> 6) & 7;
    int kc   = t >> 9;
    int krow = kc * 32 + ((lane >> 4) * 8);
    int col  = cb * 16 + (lane & 15);

    unsigned short h8[8], l8[8];
    #pragma unroll
    for (int j = 0; j < 8; ++j) {
        float f = W[(krow + j) * D + col];
        unsigned short h = f2bf(f);
        float hf = __uint_as_float(((unsigned int)h) << 16);
        h8[j] = h;
        l8[j] = f2bf(f - hf);
    }
    #pragma unroll
    for (int j = 0; j < 8; ++j) { whi[t * 8 + j] = h8[j]; wlo[t * 8 + j] = l8[j]; }
}

// ---------------------------------------------------------------------------
// Y[bf16] = (RELU_IN ? relu(X) : X) @ W  via 16x16x32 bf16 MFMA.
// R6: 512 threads (8 waves), 256 rows per block. LDS 64 KB -> 2 blocks/CU
// -> 16 waves/CU (4/SIMD). Half the blocks of R5 => half the W staging,
// 2x resident MFMA streams. Wave micro-kernel unchanged (operands swapped:
// D holds Y^T tiles -> packed 8-B bf16 column stores).
// ---------------------------------------------------------------------------
template<int RELU_IN, int SPLIT_X>
__global__ __launch_bounds__(512) void k_gemm_mfma(const void* __restrict__ Xv,
                                                   const unsigned short* __restrict__ whi,
                                                   const unsigned short* __restrict__ wlo,
                                                   unsigned short* __restrict__ Y) {
    __shared__ short wl_hi[16384];   // 32 KB
    __shared__ short wl_lo[16384];   // 32 KB

    const int tid = threadIdx.x;

    {
        const float4* sh = (const float4*)whi;
        const float4* sl = (const float4*)wlo;
        float4* dh = (float4*)wl_hi;
        float4* dl = (float4*)wl_lo;
        #pragma unroll
        for (int i = tid; i < 2048; i += 512) { dh[i] = sh[i]; dl[i] = sl[i]; }
    }
    __syncthreads();

    const int wave = tid >> 6;           // 0..7
    const int lane = tid & 63;
    const int lrow = lane & 15;
    const int kgrp = lane >> 4;
    const int row_base = blockIdx.x * 256 + wave * 32;

    const float*          Xf = (const float*)Xv;
    const unsigned short* Xb = (const unsigned short*)Xv;

    f32x4 acc[2][8];
    #pragma unroll
    for (int rg = 0; rg < 2; ++rg)
        #pragma unroll
        for (int cb = 0; cb < 8; ++cb)
            acc[rg][cb] = (f32x4){0.f, 0.f, 0.f, 0.f};

    #pragma unroll
    for (int kc = 0; kc < 4; ++kc) {
        const int kof = kc * 32 + kgrp * 8;

        short8v xh[2], xl[2];
        #pragma unroll
        for (int rg = 0; rg < 2; ++rg) {
            const int row = row_base + rg * 16 + lrow;
            if (SPLIT_X) {
                float fv[8];
                if (row < N_NODES) {
                    const float* p = Xf + (size_t)row * D + kof;
                    float4 a = *(const float4*)p;
                    float4 b = *(const float4*)(p + 4);
                    fv[0] = a.x; fv[1] = a.y; fv[2] = a.z; fv[3] = a.w;
                    fv[4] = b.x; fv[5] = b.y; fv[6] = b.z; fv[7] = b.w;
                } else {
                    #pragma unroll
                    for (int j = 0; j < 8; ++j) fv[j] = 0.f;
                }
                #pragma unroll
                for (int j = 0; j < 8; ++j) {
                    float f = RELU_IN ? fmaxf(fv[j], 0.f) : fv[j];
                    unsigned short h = f2bf(f);
                    float hf = __uint_as_float(((unsigned int)h) << 16);
                    xh[rg][j] = (short)h;
                    xl[rg][j] = (short)f2bf(f - hf);
                }
            } else {
                short8v v = {0, 0, 0, 0, 0, 0, 0, 0};
                if (row < N_NODES)
                    v = *(const short8v*)(Xb + (size_t)row * D + kof);
                if (RELU_IN) {
                    #pragma unroll
                    for (int j = 0; j < 8; ++j)
                        if (((unsigned short)v[j]) & 0x8000u) v[j] = 0;
                }
                xh[rg] = v;
            }
        }

        #pragma unroll
        for (int cb = 0; cb < 8; ++cb) {
            const int fo = ((kc * 8 + cb) * 64 + lane) * 8;
            short8v bh = *(const short8v*)&wl_hi[fo];
            short8v bl = *(const short8v*)&wl_lo[fo];
            #pragma unroll
            for (int rg = 0; rg < 2; ++rg) {
                acc[rg][cb] = __builtin_amdgcn_mfma_f32_16x16x32_bf16(bh, xh[rg], acc[rg][cb], 0, 0, 0);
                acc[rg][cb] = __builtin_amdgcn_mfma_f32_16x16x32_bf16(bl, xh[rg], acc[rg][cb], 0, 0, 0);
                if (SPLIT_X)
                    acc[rg][cb] = __builtin_amdgcn_mfma_f32_16x16x32_bf16(bh, xl[rg], acc[rg][cb], 0, 0, 0);
            }
        }
    }

    #pragma unroll
    for (int rg = 0; rg < 2; ++rg) {
        const int row = row_base + rg * 16 + lrow;
        if (row >= N_NODES) continue;
        #pragma unroll
        for (int cb = 0; cb < 8; ++cb) {
            f32x4 a = acc[rg][cb];
            unsigned int p0 = (unsigned int)f2bf(a[0]) | ((unsigned int)f2bf(a[1]) << 16);
            unsigned int p1 = (unsigned int)f2bf(a[2]) | ((unsigned int)f2bf(a[3]) << 16);
            uint2 pv; pv.x = p0; pv.y = p1;
            *(uint2*)(Y + (size_t)row * D + cb * 16 + kgrp * 4) = pv;
        }
    }
}

// ---------------------------------------------------------------------------
// Gather-aggregate: one wave per node, scalar (wave-uniform) CSR reads,
// 8-deep gather batches with clamp + nrm=0 masking.
// ---------------------------------------------------------------------------
__global__ __launch_bounds__(256) void k_agg(const unsigned int* __restrict__ Hb,
                                             const float* __restrict__ dis,
                                             const float* __restrict__ bias,
                                             const int* __restrict__ off,
                                             const int* __restrict__ csr_src,
                                             const float* __restrict__ csr_nrm,
                                             unsigned int* __restrict__ AGGb) {
    int wid = (blockIdx.x * 256 + threadIdx.x) >> 6;
    if (wid >= N_NODES) return;
    int lane = threadIdx.x & 63;

    int jb = __builtin_amdgcn_readfirstlane(off[wid]);
    int je = __builtin_amdgcn_readfirstlane(off[wid + 1]);

    float2 b = ((const float2*)bias)[lane];
    float dn = dis[wid];
    float dn2 = dn * dn;
    unsigned int self = Hb[(size_t)wid * 64 + lane];
    float accx = b.x + dn2 * bflo2f(self);
    float accy = b.y + dn2 * bfhi2f(self);

    for (int base = jb; base < je; base += 8) {
        int   si[8];
        float ni[8];
        #pragma unroll
        for (int i = 0; i < 8; ++i) {
            int j = base + i;
            int jc = (j < je) ? j : (je - 1);
            si[i] = csr_src[jc];
            float n = csr_nrm[jc];
            ni[i] = (j < je) ? n : 0.f;
        }
        unsigned int v[8];
        #pragma unroll
        for (int i = 0; i < 8; ++i)
            v[i] = Hb[(size_t)si[i] * 64 + lane];
        #pragma unroll
        for (int i = 0; i < 8; ++i) {
            accx += ni[i] * bflo2f(v[i]);
            accy += ni[i] * bfhi2f(v[i]);
        }
    }
    unsigned int o = (unsigned int)f2bf(accx) | (((unsigned int)f2bf(accy)) << 16);
    AGGb[(size_t)wid * 64 + lane] = o;
}

// ---------------------------------------------------------------------------
// One block (512 thr) per graph: relu + mean-pool (bf16 in) + linear head
// ---------------------------------------------------------------------------
__global__ __launch_bounds__(512) void k_pool_head(const unsigned short* __restrict__ Hb,
                                                   const int* __restrict__ batch,
                                                   const float* __restrict__ Wl,
                                                   const float* __restrict__ bl,
                                                   float* __restrict__ out) {
    int g   = blockIdx.x;
    int tid = threadIdx.x;
    int f   = tid & 127;
    int q   = tid >> 7;

    int lo = 0, hi = N_NODES;
    while (lo < hi) { int mid = (lo + hi) >> 1; if (batch[mid] < g) lo = mid + 1; else hi = mid; }
    int s = lo;
    lo = s; hi = N_NODES;
    while (lo < hi) { int mid = (lo + hi) >> 1; if (batch[mid] < g + 1) lo = mid + 1; else hi = mid; }
    int e = lo;

    float sum = 0.f;
    for (int i = s + q; i < e; i += 4) {
        float v = __uint_as_float(((unsigned int)Hb[(size_t)i * D + f]) << 16);
        sum += fmaxf(v, 0.f);
    }

    __shared__ float sh[4][128];
    sh[q][f] = sum;
    __syncthreads();

    __shared__ float s0[128];
    __shared__ float s1[128];
    if (tid < 128) {
        float cnt = (float)((e - s) > 0 ? (e - s) : 1);
        float p   = (sh[0][f] + sh[1][f] + sh[2][f] + sh[3][f]) / cnt;
        s0[f] = p * Wl[f * 2 + 0];
        s1[f] = p * Wl[f * 2 + 1];
    }
    __syncthreads();
    #pragma unroll
    for (int o = 64; o > 0; o >>= 1) {
        if (tid < o) { s0[tid] += s0[tid + o]; s1[tid] += s1[tid + o]; }
        __syncthreads();
    }
    if (tid == 0) {
        out[g * 2 + 0] = s0[0] + bl[0];
        out[g * 2 + 1] = s1[0] + bl[1];
    }
}

// ---------------------------------------------------------------------------
extern "C" void kernel_launch(void* const* d_in, const int* in_sizes, int n_in,
                              void* d_out, int out_size, void* d_ws, size_t ws_size,
                              hipStream_t stream) {
    const float* x     = (const float*)d_in[0];
    const int*   ei    = (const int*)  d_in[1];
    const int*   batch = (const int*)  d_in[2];
    const float* W1    = (const float*)d_in[3];
    const float* b1    = (const float*)d_in[4];
    const float* W2    = (const float*)d_in[5];
    const float* b2    = (const float*)d_in[6];
    const float* Wl    = (const float*)d_in[7];
    const float* bl    = (const float*)d_in[8];
    float* out = (float*)d_out;

    char* ws = (char*)d_ws;
    unsigned short* HbA = (unsigned short*)(ws);               // 25.6 MB bf16
    unsigned short* HbB = (unsigned short*)(ws + 25600000);    // 25.6 MB bf16
    float* dis        = (float*)(ws + 51200000);               // 400 KB
    int*   cnt        = (int*)  (ws + 51600000);               // 400 KB
    int*   off        = (int*)  (ws + 52000000);               // 400 KB + 16
    int*   pos        = (int*)  (ws + 52400016);               // 400 KB
    int*   chunk_sums = (int*)  (ws + 52800016);               // 1 KB
    int*   chunk_offs = (int*)  (ws + 52801040);               // 1 KB
    int*   csr_src    = (int*)  (ws + 52802064);               // 2.4 MB
    float* csr_nrm    = (float*)(ws + 55202064);               // 2.4 MB
    unsigned short* whi1 = (unsigned short*)(ws + 57602064);   // 32 KB
    unsigned short* wlo1 = (unsigned short*)(ws + 57634832);   // 32 KB
    unsigned short* whi2 = (unsigned short*)(ws + 57667600);   // 32 KB
    unsigned short* wlo2 = (unsigned short*)(ws + 57700368);   // 32 KB

    const int* srcIdx = ei;
    const int* dstIdx = ei + N_EDGES;

    // ---- W pre-split (both layers, one launch) ----
    k_wsplit2<<<16, 256, 0, stream>>>(W1, W2, whi1, wlo1, whi2, wlo2);

    // ---- CSR build ----
    k_zero2<<<(N_NODES + 255) / 256, 256, 0, stream>>>(cnt, pos);
    k_hist <<<(N_EDGES + 255) / 256, 256, 0, stream>>>(dstIdx, cnt);
    k_scanA<<<NB, CH, 0, stream>>>(cnt, off, chunk_sums, dis);
    k_scanB<<<1,  CH, 0, stream>>>(chunk_sums, chunk_offs, off);
    k_scanC<<<NB, CH, 0, stream>>>(off, chunk_offs);
    k_fill <<<(N_EDGES + 255) / 256, 256, 0, stream>>>(srcIdx, dstIdx, dis, off, pos,
                                                       csr_src, csr_nrm);

    const int gemm_grid = (N_NODES + 255) / 256;   // 391 blocks, 256 rows each
    const int agg_grid  = (N_NODES * 64 + 255) / 256;

    // ---- layer 1 ----
    k_gemm_mfma<0, 1><<<gemm_grid, 512, 0, stream>>>(x, whi1, wlo1, HbA);
    k_agg<<<agg_grid, 256, 0, stream>>>((const unsigned int*)HbA, dis, b1, off,
                                        csr_src, csr_nrm, (unsigned int*)HbB);
    // ---- layer 2 (relu fused into GEMM input) ----
    k_gemm_mfma<1, 0><<<gemm_grid, 512, 0, stream>>>(HbB, whi2, wlo2, HbA);
    k_agg<<<agg_grid, 256, 0, stream>>>((const unsigned int*)HbA, dis, b2, off,
                                        csr_src, csr_nrm, (unsigned int*)HbB);
    // ---- relu + mean-pool + head ----
    k_pool_head<<<N_GRAPHS, 512, 0, stream>>>(HbB, batch, Wl, bl, out);
}

// Round 8
// 281.657 us; speedup vs baseline: 8.4913x; 1.0419x over previous
//
#include <hip/hip_runtime.h>
#include <hip/hip_bf16.h>

#define N_NODES  100000
#define N_EDGES  600000
#define D        128
#define N_GRAPHS 512

#define CH   512
#define NB   ((N_NODES + CH - 1) / CH)

typedef __attribute__((ext_vector_type(8))) short      short8v;
typedef __attribute__((ext_vector_type(4))) float      f32x4;

// float -> bf16 (RNE) on raw bits
__device__ __forceinline__ unsigned short f2bf(float f) {
    unsigned int u = __float_as_uint(f);
    u += 0x7fffu + ((u >> 16) & 1u);
    return (unsigned short)(u >> 16);
}
__device__ __forceinline__ float bflo2f(unsigned int p) { return __uint_as_float(p << 16); }
__device__ __forceinline__ float bfhi2f(unsigned int p) { return __uint_as_float(p & 0xffff0000u); }

// ---------------------------------------------------------------------------
// k_pre: zero cnt + pre-split W1/W2 into MFMA B-fragments (bf16 hi/lo).
// Fragment t = kc*512 + cb*64 + lane, elem j: W[kc*32+(lane>>4)*8+j][cb*16+(lane&15)]
// ---------------------------------------------------------------------------
__global__ __launch_bounds__(256) void k_pre(const float* __restrict__ W1,
                                             const float* __restrict__ W2,
                                             unsigned short* __restrict__ whi1,
                                             unsigned short* __restrict__ wlo1,
                                             unsigned short* __restrict__ whi2,
                                             unsigned short* __restrict__ wlo2,
                                             int* __restrict__ cnt) {
    int tt = blockIdx.x * 256 + threadIdx.x;
    if (tt < N_NODES) cnt[tt] = 0;
    if (tt >= 4096) return;
    const float* W = (tt < 2048) ? W1 : W2;
    unsigned short* whi = (tt < 2048) ? whi1 : whi2;
    unsigned short* wlo = (tt < 2048) ? wlo1 : wlo2;
    int t = tt & 2047;

    int lane = t & 63;
    int cb   = (t >> 6) & 7;
    int kc   = t >> 9;
    int krow = kc * 32 + ((lane >> 4) * 8);
    int col  = cb * 16 + (lane & 15);

    unsigned short h8[8], l8[8];
    #pragma unroll
    for (int j = 0; j < 8; ++j) {
        float f = W[(krow + j) * D + col];
        unsigned short h = f2bf(f);
        float hf = __uint_as_float(((unsigned int)h) << 16);
        h8[j] = h;
        l8[j] = f2bf(f - hf);
    }
    #pragma unroll
    for (int j = 0; j < 8; ++j) { whi[t * 8 + j] = h8[j]; wlo[t * 8 + j] = l8[j]; }
}

__global__ void k_hist(const int* __restrict__ dst, int* __restrict__ cnt) {
    int e = blockIdx.x * blockDim.x + threadIdx.x;
    if (e < N_EDGES) atomicAdd(&cnt[dst[e]], 1);
}

// ---------------------------------------------------------------------------
// 3-pass exclusive scan of cnt -> off; scanA also emits dis; scanC also
// seeds pos = off (fill's running cursor).
// ---------------------------------------------------------------------------
__global__ __launch_bounds__(CH) void k_scanA(const int* __restrict__ cnt,
                                              int* __restrict__ off,
                                              int* __restrict__ chunk_sums,
                                              float* __restrict__ dis) {
    __shared__ int s[CH];
    int tid = threadIdx.x;
    int gid = blockIdx.x * CH + tid;
    int v = (gid < N_NODES) ? cnt[gid] : 0;
    if (gid < N_NODES) dis[gid] = rsqrtf((float)(v + 1));
    s[tid] = v;
    __syncthreads();
    #pragma unroll
    for (int o = 1; o < CH; o <<= 1) {
        int t = (tid >= o) ? s[tid - o] : 0;
        __syncthreads();
        s[tid] += t;
        __syncthreads();
    }
    if (gid < N_NODES) off[gid] = s[tid] - v;
    if (tid == CH - 1) chunk_sums[blockIdx.x] = s[tid];
}

__global__ __launch_bounds__(CH) void k_scanB(const int* __restrict__ chunk_sums,
                                              int* __restrict__ chunk_offs,
                                              int* __restrict__ off) {
    __shared__ int s[CH];
    int tid = threadIdx.x;
    int v = (tid < NB) ? chunk_sums[tid] : 0;
    s[tid] = v;
    __syncthreads();
    #pragma unroll
    for (int o = 1; o < CH; o <<= 1) {
        int t = (tid >= o) ? s[tid - o] : 0;
        __syncthreads();
        s[tid] += t;
        __syncthreads();
    }
    if (tid < NB) chunk_offs[tid] = s[tid] - v;
    if (tid == NB - 1) off[N_NODES] = s[tid];
}

__global__ __launch_bounds__(CH) void k_scanC(int* __restrict__ off,
                                              const int* __restrict__ chunk_offs,
                                              int* __restrict__ pos) {
    int gid = blockIdx.x * CH + threadIdx.x;
    if (gid < N_NODES) {
        int v = off[gid] + chunk_offs[blockIdx.x];
        off[gid] = v;
        pos[gid] = v;
    }
}

__global__ void k_fill(const int* __restrict__ src, const int* __restrict__ dst,
                       const float* __restrict__ dis,
                       int* __restrict__ pos,
                       int* __restrict__ csr_src, float* __restrict__ csr_nrm) {
    int e = blockIdx.x * blockDim.x + threadIdx.x;
    if (e >= N_EDGES) return;
    int s = src[e];
    int d = dst[e];
    int j = atomicAdd(&pos[d], 1);
    csr_src[j] = s;
    csr_nrm[j] = dis[s] * dis[d];
}

// ---------------------------------------------------------------------------
// Y[bf16] = (RELU_IN ? relu(X) : X) @ W  via 16x16x32 bf16 MFMA.
// R7: phase-split — ALL global X loads issued first into static registers,
// then convert, then MFMA (one vmem latency exposure per wave, not four).
// 512 thr / 8 waves / 256 rows per block; W fragments in 64 KB LDS.
// Operands swapped (W first) -> D holds Y^T -> packed 8-B bf16 column stores.
// ---------------------------------------------------------------------------
template<int RELU_IN, int SPLIT_X>
__global__ __launch_bounds__(512) void k_gemm_mfma(const void* __restrict__ Xv,
                                                   const unsigned short* __restrict__ whi,
                                                   const unsigned short* __restrict__ wlo,
                                                   unsigned short* __restrict__ Y) {
    __shared__ short wl_hi[16384];   // 32 KB
    __shared__ short wl_lo[16384];   // 32 KB

    const int tid = threadIdx.x;

    {
        const float4* sh = (const float4*)whi;
        const float4* sl = (const float4*)wlo;
        float4* dh = (float4*)wl_hi;
        float4* dl = (float4*)wl_lo;
        #pragma unroll
        for (int i = tid; i < 2048; i += 512) { dh[i] = sh[i]; dl[i] = sl[i]; }
    }
    __syncthreads();

    const int wave = tid >> 6;           // 0..7
    const int lane = tid & 63;
    const int lrow = lane & 15;
    const int kgrp = lane >> 4;          // 0..3
    const int row_base = blockIdx.x * 256 + wave * 32;

    const float*          Xf = (const float*)Xv;
    const unsigned short* Xb = (const unsigned short*)Xv;

    f32x4 acc[2][8];
    #pragma unroll
    for (int rg = 0; rg < 2; ++rg)
        #pragma unroll
        for (int cb = 0; cb < 8; ++cb)
            acc[rg][cb] = (f32x4){0.f, 0.f, 0.f, 0.f};

    if (SPLIT_X) {
        // ---- phase 1: all 16 loads in flight ----
        float4 xr[4][2][2];
        #pragma unroll
        for (int kc = 0; kc < 4; ++kc)
            #pragma unroll
            for (int rg = 0; rg < 2; ++rg) {
                const int row = row_base + rg * 16 + lrow;
                if (row < N_NODES) {
                    const float* p = Xf + (size_t)row * D + kc * 32 + kgrp * 8;
                    xr[kc][rg][0] = *(const float4*)p;
                    xr[kc][rg][1] = *(const float4*)(p + 4);
                } else {
                    xr[kc][rg][0] = make_float4(0.f, 0.f, 0.f, 0.f);
                    xr[kc][rg][1] = make_float4(0.f, 0.f, 0.f, 0.f);
                }
            }
        // ---- phase 2+3: per kc convert then MFMA ----
        #pragma unroll
        for (int kc = 0; kc < 4; ++kc) {
            short8v xh[2], xl[2];
            #pragma unroll
            for (int rg = 0; rg < 2; ++rg) {
                float fv[8];
                fv[0] = xr[kc][rg][0].x; fv[1] = xr[kc][rg][0].y;
                fv[2] = xr[kc][rg][0].z; fv[3] = xr[kc][rg][0].w;
                fv[4] = xr[kc][rg][1].x; fv[5] = xr[kc][rg][1].y;
                fv[6] = xr[kc][rg][1].z; fv[7] = xr[kc][rg][1].w;
                #pragma unroll
                for (int j = 0; j < 8; ++j) {
                    float f = RELU_IN ? fmaxf(fv[j], 0.f) : fv[j];
                    unsigned short h = f2bf(f);
                    float hf = __uint_as_float(((unsigned int)h) << 16);
                    xh[rg][j] = (short)h;
                    xl[rg][j] = (short)f2bf(f - hf);
                }
            }
            #pragma unroll
            for (int cb = 0; cb < 8; ++cb) {
                const int fo = ((kc * 8 + cb) * 64 + lane) * 8;
                short8v bh = *(const short8v*)&wl_hi[fo];
                short8v bl = *(const short8v*)&wl_lo[fo];
                #pragma unroll
                for (int rg = 0; rg < 2; ++rg) {
                    acc[rg][cb] = __builtin_amdgcn_mfma_f32_16x16x32_bf16(bh, xh[rg], acc[rg][cb], 0, 0, 0);
                    acc[rg][cb] = __builtin_amdgcn_mfma_f32_16x16x32_bf16(bl, xh[rg], acc[rg][cb], 0, 0, 0);
                    acc[rg][cb] = __builtin_amdgcn_mfma_f32_16x16x32_bf16(bh, xl[rg], acc[rg][cb], 0, 0, 0);
                }
            }
        }
    } else {
        // ---- phase 1: all 8 loads in flight ----
        short8v xrb[4][2];
        #pragma unroll
        for (int kc = 0; kc < 4; ++kc)
            #pragma unroll
            for (int rg = 0; rg < 2; ++rg) {
                const int row = row_base + rg * 16 + lrow;
                short8v v = {0, 0, 0, 0, 0, 0, 0, 0};
                if (row < N_NODES)
                    v = *(const short8v*)(Xb + (size_t)row * D + kc * 32 + kgrp * 8);
                xrb[kc][rg] = v;
            }
        #pragma unroll
        for (int kc = 0; kc < 4; ++kc) {
            short8v xh[2];
            #pragma unroll
            for (int rg = 0; rg < 2; ++rg) {
                short8v v = xrb[kc][rg];
                if (RELU_IN) {
                    #pragma unroll
                    for (int j = 0; j < 8; ++j)
                        if (((unsigned short)v[j]) & 0x8000u) v[j] = 0;
                }
                xh[rg] = v;
            }
            #pragma unroll
            for (int cb = 0; cb < 8; ++cb) {
                const int fo = ((kc * 8 + cb) * 64 + lane) * 8;
                short8v bh = *(const short8v*)&wl_hi[fo];
                short8v bl = *(const short8v*)&wl_lo[fo];
                #pragma unroll
                for (int rg = 0; rg < 2; ++rg) {
                    acc[rg][cb] = __builtin_amdgcn_mfma_f32_16x16x32_bf16(bh, xh[rg], acc[rg][cb], 0, 0, 0);
                    acc[rg][cb] = __builtin_amdgcn_mfma_f32_16x16x32_bf16(bl, xh[rg], acc[rg][cb], 0, 0, 0);
                }
            }
        }
    }

    #pragma unroll
    for (int rg = 0; rg < 2; ++rg) {
        const int row = row_base + rg * 16 + lrow;
        if (row >= N_NODES) continue;
        #pragma unroll
        for (int cb = 0; cb < 8; ++cb) {
            f32x4 a = acc[rg][cb];
            unsigned int p0 = (unsigned int)f2bf(a[0]) | ((unsigned int)f2bf(a[1]) << 16);
            unsigned int p1 = (unsigned int)f2bf(a[2]) | ((unsigned int)f2bf(a[3]) << 16);
            uint2 pv; pv.x = p0; pv.y = p1;
            *(uint2*)(Y + (size_t)row * D + cb * 16 + kgrp * 4) = pv;
        }
    }
}

// ---------------------------------------------------------------------------
// Gather-aggregate v4: one wave per node, half-wave edge split.
// Lanes 0-31 process edges {base..base+3}, lanes 32-63 edges {base+4..base+7};
// each lane gathers uint2 (4 bf16 cols). CSR reads stay wave-uniform scalar.
// Cross-half shfl-add at the end; lanes 0-31 store the row.
// ---------------------------------------------------------------------------
__global__ __launch_bounds__(256) void k_agg(const uint2* __restrict__ Hb2,
                                             const float* __restrict__ dis,
                                             const float* __restrict__ bias,
                                             const int* __restrict__ off,
                                             const int* __restrict__ csr_src,
                                             const float* __restrict__ csr_nrm,
                                             uint2* __restrict__ AGGb2) {
    int wid = (blockIdx.x * 256 + threadIdx.x) >> 6;
    if (wid >= N_NODES) return;
    int lane = threadIdx.x & 63;
    int cg   = lane & 31;     // col group: 4 bf16
    int half = lane >> 5;     // 0/1

    int jb = __builtin_amdgcn_readfirstlane(off[wid]);
    int je = __builtin_amdgcn_readfirstlane(off[wid + 1]);

    float4 acc;
    {
        uint2 self = Hb2[(size_t)wid * 32 + cg];
        float4 b = ((const float4*)bias)[cg];
        float dn = dis[wid];
        float dn2 = dn * dn;
        acc.x = b.x + dn2 * bflo2f(self.x);
        acc.y = b.y + dn2 * bfhi2f(self.x);
        acc.z = b.z + dn2 * bflo2f(self.y);
        acc.w = b.w + dn2 * bfhi2f(self.y);
        if (half) { acc.x = 0.f; acc.y = 0.f; acc.z = 0.f; acc.w = 0.f; }
    }

    for (int base = jb; base < je; base += 8) {
        int   sv[8];
        float nv[8];
        #pragma unroll
        for (int i = 0; i < 8; ++i) {
            int j  = base + i;
            int jc = (j < je) ? j : (je - 1);   // always a valid edge
            sv[i]  = csr_src[jc];               // uniform -> s_load
            float n = csr_nrm[jc];              // uniform -> s_load
            nv[i]  = (j < je) ? n : 0.f;
        }
        uint2 g[4];
        float nn[4];
        #pragma unroll
        for (int i = 0; i < 4; ++i) {
            int s  = half ? sv[i + 4] : sv[i];
            nn[i]  = half ? nv[i + 4] : nv[i];
            g[i] = Hb2[(size_t)s * 32 + cg];    // 4 uint2 loads in flight/half
        }
        #pragma unroll
        for (int i = 0; i < 4; ++i) {
            acc.x += nn[i] * bflo2f(g[i].x);
            acc.y += nn[i] * bfhi2f(g[i].x);
            acc.z += nn[i] * bflo2f(g[i].y);
            acc.w += nn[i] * bfhi2f(g[i].y);
        }
    }

    // cross-half reduce: lane l <-> l^32
    acc.x += __shfl(acc.x, lane ^ 32);
    acc.y += __shfl(acc.y, lane ^ 32);
    acc.z += __shfl(acc.z, lane ^ 32);
    acc.w += __shfl(acc.w, lane ^ 32);

    if (half == 0) {
        uint2 o;
        o.x = (unsigned int)f2bf(acc.x) | (((unsigned int)f2bf(acc.y)) << 16);
        o.y = (unsigned int)f2bf(acc.z) | (((unsigned int)f2bf(acc.w)) << 16);
        AGGb2[(size_t)wid * 32 + cg] = o;
    }
}

// ---------------------------------------------------------------------------
// One block (512 thr) per graph: relu + mean-pool + linear head.
// Thread = (colpair 0..63) x (row-phase 0..7): uint loads, 256 B/wave/row.
// ---------------------------------------------------------------------------
__global__ __launch_bounds__(512) void k_pool_head(const unsigned int* __restrict__ Hu,
                                                   const int* __restrict__ batch,
                                                   const float* __restrict__ Wl,
                                                   const float* __restrict__ bl,
                                                   float* __restrict__ out) {
    int g   = blockIdx.x;
    int tid = threadIdx.x;
    int cp  = tid & 63;   // colpair -> cols 2cp, 2cp+1
    int q   = tid >> 6;   // 0..7

    int lo = 0, hi = N_NODES;
    while (lo < hi) { int mid = (lo + hi) >> 1; if (batch[mid] < g) lo = mid + 1; else hi = mid; }
    int s = lo;
    lo = s; hi = N_NODES;
    while (lo < hi) { int mid = (lo + hi) >> 1; if (batch[mid] < g + 1) lo = mid + 1; else hi = mid; }
    int e = lo;

    float sx = 0.f, sy = 0.f;
    for (int i = s + q; i < e; i += 8) {
        unsigned int v = Hu[(size_t)i * 64 + cp];
        sx += fmaxf(bflo2f(v), 0.f);
        sy += fmaxf(bfhi2f(v), 0.f);
    }

    __shared__ float shx[8][64];
    __shared__ float shy[8][64];
    shx[q][cp] = sx;
    shy[q][cp] = sy;
    __syncthreads();

    __shared__ float s0[64];
    __shared__ float s1[64];
    if (tid < 64) {
        float cnt = (float)((e - s) > 0 ? (e - s) : 1);
        float px = 0.f, py = 0.f;
        #pragma unroll
        for (int r = 0; r < 8; ++r) { px += shx[r][tid]; py += shy[r][tid]; }
        px /= cnt; py /= cnt;
        s0[tid] = px * Wl[4 * tid + 0] + py * Wl[4 * tid + 2];
        s1[tid] = px * Wl[4 * tid + 1] + py * Wl[4 * tid + 3];
    }
    __syncthreads();
    #pragma unroll
    for (int o = 32; o > 0; o >>= 1) {
        if (tid < o) { s0[tid] += s0[tid + o]; s1[tid] += s1[tid + o]; }
        __syncthreads();
    }
    if (tid == 0) {
        out[g * 2 + 0] = s0[0] + bl[0];
        out[g * 2 + 1] = s1[0] + bl[1];
    }
}

// ---------------------------------------------------------------------------
extern "C" void kernel_launch(void* const* d_in, const int* in_sizes, int n_in,
                              void* d_out, int out_size, void* d_ws, size_t ws_size,
                              hipStream_t stream) {
    const float* x     = (const float*)d_in[0];
    const int*   ei    = (const int*)  d_in[1];
    const int*   batch = (const int*)  d_in[2];
    const float* W1    = (const float*)d_in[3];
    const float* b1    = (const float*)d_in[4];
    const float* W2    = (const float*)d_in[5];
    const float* b2    = (const float*)d_in[6];
    const float* Wl    = (const float*)d_in[7];
    const float* bl    = (const float*)d_in[8];
    float* out = (float*)d_out;

    char* ws = (char*)d_ws;
    unsigned short* HbA = (unsigned short*)(ws);               // 25.6 MB bf16
    unsigned short* HbB = (unsigned short*)(ws + 25600000);    // 25.6 MB bf16
    float* dis        = (float*)(ws + 51200000);               // 400 KB
    int*   cnt        = (int*)  (ws + 51600000);               // 400 KB
    int*   off        = (int*)  (ws + 52000000);               // 400 KB + 16
    int*   pos        = (int*)  (ws + 52400016);               // 400 KB
    int*   chunk_sums = (int*)  (ws + 52800016);               // 1 KB
    int*   chunk_offs = (int*)  (ws + 52801040);               // 1 KB
    int*   csr_src    = (int*)  (ws + 52802064);               // 2.4 MB
    float* csr_nrm    = (float*)(ws + 55202064);               // 2.4 MB
    unsigned short* whi1 = (unsigned short*)(ws + 57602064);   // 32 KB
    unsigned short* wlo1 = (unsigned short*)(ws + 57634832);   // 32 KB
    unsigned short* whi2 = (unsigned short*)(ws + 57667600);   // 32 KB
    unsigned short* wlo2 = (unsigned short*)(ws + 57700368);   // 32 KB

    const int* srcIdx = ei;
    const int* dstIdx = ei + N_EDGES;

    // ---- pre: zero cnt + W split (one launch) ----
    k_pre <<<(N_NODES + 255) / 256, 256, 0, stream>>>(W1, W2, whi1, wlo1, whi2, wlo2, cnt);
    // ---- CSR build ----
    k_hist <<<(N_EDGES + 255) / 256, 256, 0, stream>>>(dstIdx, cnt);
    k_scanA<<<NB, CH, 0, stream>>>(cnt, off, chunk_sums, dis);
    k_scanB<<<1,  CH, 0, stream>>>(chunk_sums, chunk_offs, off);
    k_scanC<<<NB, CH, 0, stream>>>(off, chunk_offs, pos);
    k_fill <<<(N_EDGES + 255) / 256, 256, 0, stream>>>(srcIdx, dstIdx, dis, pos,
                                                       csr_src, csr_nrm);

    const int gemm_grid = (N_NODES + 255) / 256;   // 391 blocks, 256 rows each
    const int agg_grid  = (N_NODES * 64 + 255) / 256;

    // ---- layer 1 ----
    k_gemm_mfma<0, 1><<<gemm_grid, 512, 0, stream>>>(x, whi1, wlo1, HbA);
    k_agg<<<agg_grid, 256, 0, stream>>>((const uint2*)HbA, dis, b1, off,
                                        csr_src, csr_nrm, (uint2*)HbB);
    // ---- layer 2 (relu fused into GEMM input) ----
    k_gemm_mfma<1, 0><<<gemm_grid, 512, 0, stream>>>(HbB, whi2, wlo2, HbA);
    k_agg<<<agg_grid, 256, 0, stream>>>((const uint2*)HbA, dis, b2, off,
                                        csr_src, csr_nrm, (uint2*)HbB);
    // ---- relu + mean-pool + head ----
    k_pool_head<<<N_GRAPHS, 512, 0, stream>>>((const unsigned int*)HbB, batch, Wl, bl, out);
}